// Round 2
// baseline (5255.098 us; speedup 1.0000x reference)
//
#include <hip/hip_runtime.h>
#include <cstddef>
#include <cstdint>

#define N_NODES  200000
#define N_EDGES  3200000
#define N_GRAPHS 2000
#define BN_EPS   1e-5f

typedef unsigned int   u32;
typedef unsigned short u16;

// ---------------------------------------------------------------------------
// bf16 helpers (raw-bit, RNE pack)
// ---------------------------------------------------------------------------
__device__ __forceinline__ float bflo(u32 v) { union {u32 i; float f;} c; c.i = v << 16; return c.f; }
__device__ __forceinline__ float bfhi(u32 v) { union {u32 i; float f;} c; c.i = v & 0xffff0000u; return c.f; }
__device__ __forceinline__ float bf1(u16 v)  { union {u32 i; float f;} c; c.i = ((u32)v) << 16; return c.f; }
__device__ __forceinline__ u32 f2bf(float f) {
    union {float f; u32 i;} c; c.f = f;
    return (c.i + 0x7fffu + ((c.i >> 16) & 1u)) >> 16;
}
__device__ __forceinline__ u32 pack2(float a, float b) { return f2bf(a) | (f2bf(b) << 16); }

// ---------------------------------------------------------------------------
// degree / norm
// ---------------------------------------------------------------------------
__global__ void deg_kernel(const int* __restrict__ dst, int* __restrict__ deg, int e) {
    int i = blockIdx.x * 256 + threadIdx.x;
    if (i < e) atomicAdd(&deg[dst[i]], 1);
}

__global__ void norm_kernel(const int* __restrict__ deg, float* __restrict__ norm, int n) {
    int i = blockIdx.x * 256 + threadIdx.x;
    if (i < n) {
        int d = deg[i];
        norm[i] = (d > 0) ? rsqrtf((float)d) : 0.f;
    }
}

// ---------------------------------------------------------------------------
// x (fp32) -> bf16
// ---------------------------------------------------------------------------
__global__ void x2bf_kernel(const float* __restrict__ x, u16* __restrict__ xb, int total4) {
    for (int i = blockIdx.x * 256 + threadIdx.x; i < total4; i += gridDim.x * 256) {
        float4 v = ((const float4*)x)[i];
        uint2 o; o.x = pack2(v.x, v.y); o.y = pack2(v.z, v.w);
        ((uint2*)xb)[i] = o;
    }
}

// ---------------------------------------------------------------------------
// scan for CSR rowptr (chunk = 2048 per block)
// ---------------------------------------------------------------------------
__global__ void scan_block_sums(const int* __restrict__ deg, int* __restrict__ bsums, int n) {
    int base = blockIdx.x * 2048;
    int s = 0;
    for (int i = threadIdx.x; i < 2048; i += 256) {
        int idx = base + i;
        s += (idx < n) ? deg[idx] : 0;
    }
    __shared__ int ls[256];
    ls[threadIdx.x] = s;
    __syncthreads();
    for (int off = 128; off > 0; off >>= 1) {
        if (threadIdx.x < off) ls[threadIdx.x] += ls[threadIdx.x + off];
        __syncthreads();
    }
    if (threadIdx.x == 0) bsums[blockIdx.x] = ls[0];
}

__global__ void scan_exclusive_small(int* __restrict__ bsums, int nb) {
    __shared__ int ls[128];
    int t = threadIdx.x;
    int v = (t < nb) ? bsums[t] : 0;
    ls[t] = v;
    __syncthreads();
    for (int off = 1; off < 128; off <<= 1) {
        int add = (t >= off) ? ls[t - off] : 0;
        __syncthreads();
        ls[t] += add;
        __syncthreads();
    }
    if (t < nb) bsums[t] = ls[t] - v;   // exclusive
}

__global__ void scan_final(const int* __restrict__ deg, const int* __restrict__ bsums,
                           int* __restrict__ rowptr, int n) {
    int base = blockIdx.x * 2048;
    int t = threadIdx.x;
    int i0 = base + t * 8;
    int vals[8];
    int s = 0;
#pragma unroll
    for (int j = 0; j < 8; ++j) {
        int idx = i0 + j;
        vals[j] = (idx < n) ? deg[idx] : 0;
        s += vals[j];
    }
    __shared__ int ls[256];
    ls[t] = s;
    __syncthreads();
    for (int off = 1; off < 256; off <<= 1) {
        int add = (t >= off) ? ls[t - off] : 0;
        __syncthreads();
        ls[t] += add;
        __syncthreads();
    }
    int run = bsums[blockIdx.x] + ls[t] - s;   // exclusive prefix for this thread
#pragma unroll
    for (int j = 0; j < 8; ++j) {
        int idx = i0 + j;
        if (idx < n) rowptr[idx] = run;
        run += vals[j];
    }
    if (n - 1 >= i0 && n - 1 < i0 + 8) rowptr[n] = run;
}

__global__ void copy_int_kernel(const int* __restrict__ src, int* __restrict__ dst, int n) {
    int i = blockIdx.x * 256 + threadIdx.x;
    if (i < n) dst[i] = src[i];
}

__global__ void fill_csr(const int* __restrict__ esrc, const int* __restrict__ edst,
                         int* __restrict__ pos, int* __restrict__ csr, int e) {
    int i = blockIdx.x * 256 + threadIdx.x;
    if (i < e) {
        int d = edst[i];
        int slot = atomicAdd(&pos[d], 1);
        csr[slot] = esrc[i];
    }
}

// ---------------------------------------------------------------------------
// prop: p[dst] = norm[dst] * sum_{src in N(dst)} norm[src] * h[src]   (d = 128)
// bf16 in / bf16 out; one wave per node, lane handles 2 features (one u32)
// ---------------------------------------------------------------------------
__global__ __launch_bounds__(256)
void prop_kernel(const u16* __restrict__ hin, const float* __restrict__ norm,
                 const int* __restrict__ rowptr, const int* __restrict__ csr,
                 u16* __restrict__ pout, int n) {
    int wave = threadIdx.x >> 6;
    int lane = threadIdx.x & 63;
    int node = blockIdx.x * 4 + wave;
    if (node >= n) return;
    int s = rowptr[node], e = rowptr[node + 1];
    float ax = 0.f, ay = 0.f;
    int i = s;
    for (; i + 1 < e; i += 2) {
        int s0 = csr[i], s1 = csr[i + 1];
        float n0 = norm[s0], n1 = norm[s1];
        u32 v0 = ((const u32*)(hin + (size_t)s0 * 128))[lane];
        u32 v1 = ((const u32*)(hin + (size_t)s1 * 128))[lane];
        ax += bflo(v0) * n0 + bflo(v1) * n1;
        ay += bfhi(v0) * n0 + bfhi(v1) * n1;
    }
    if (i < e) {
        int s0 = csr[i];
        float n0 = norm[s0];
        u32 v0 = ((const u32*)(hin + (size_t)s0 * 128))[lane];
        ax += bflo(v0) * n0;
        ay += bfhi(v0) * n0;
    }
    float nd = norm[node];
    ((u32*)(pout + (size_t)node * 128))[lane] = pack2(ax * nd, ay * nd);
}

// ---------------------------------------------------------------------------
// GEMM: out[N, DOUT] = A0 @ W[0:128] + A1 @ W[128:256] + A2 @ W[256:384]
// A matrices are bf16, row stride 128. W fp32. Output bf16.
// Tile 64 x DOUT, K = 384, fp32 accumulation.
// ---------------------------------------------------------------------------
template <int DOUT>
__global__ __launch_bounds__(256)
void gemm_cat3(const u16* __restrict__ A0, const u16* __restrict__ A1,
               const u16* __restrict__ A2, const float* __restrict__ W,
               u16* __restrict__ outp) {
    constexpr int TPC = DOUT / 8;         // threads across columns (16 or 8)
    constexpr int RPT = 64 * TPC / 256;   // rows per thread (4 or 2)
    const int tid = threadIdx.x;
    const int tx = tid % TPC;
    const int ty = tid / TPC;
    const int row0 = blockIdx.x * 64;
    __shared__ float As[64][33];
    __shared__ float Bs[32][DOUT];
    float acc[RPT][8];
#pragma unroll
    for (int i = 0; i < RPT; ++i)
#pragma unroll
        for (int j = 0; j < 8; ++j) acc[i][j] = 0.f;

    const u16* mats[3] = {A0, A1, A2};
    for (int kb = 0; kb < 384; kb += 32) {
        const u16* M = mats[kb >> 7];
        const int kloc = kb & 127;
        {
            const int r  = tid >> 2;
            const int k0 = (tid & 3) * 8;           // 8 bf16 = 16 bytes per thread
            uint4 v = *(const uint4*)(M + (size_t)(row0 + r) * 128 + kloc + k0);
            As[r][k0 + 0] = bflo(v.x); As[r][k0 + 1] = bfhi(v.x);
            As[r][k0 + 2] = bflo(v.y); As[r][k0 + 3] = bfhi(v.y);
            As[r][k0 + 4] = bflo(v.z); As[r][k0 + 5] = bfhi(v.z);
            As[r][k0 + 6] = bflo(v.w); As[r][k0 + 7] = bfhi(v.w);
        }
        {
#pragma unroll
            for (int i = 0; i < DOUT / 32; ++i) {
                int idx = tid + i * 256;
                int k = idx / (DOUT / 4);
                int c = (idx % (DOUT / 4)) * 4;
                *(float4*)&Bs[k][c] = *(const float4*)(W + (size_t)(kb + k) * DOUT + c);
            }
        }
        __syncthreads();
#pragma unroll
        for (int kk = 0; kk < 32; ++kk) {
            float b[8];
            float4 b0 = *(const float4*)&Bs[kk][tx * 8];
            float4 b1 = *(const float4*)&Bs[kk][tx * 8 + 4];
            b[0] = b0.x; b[1] = b0.y; b[2] = b0.z; b[3] = b0.w;
            b[4] = b1.x; b[5] = b1.y; b[6] = b1.z; b[7] = b1.w;
            float a[RPT];
#pragma unroll
            for (int i = 0; i < RPT; ++i) a[i] = As[ty * RPT + i][kk];
#pragma unroll
            for (int i = 0; i < RPT; ++i)
#pragma unroll
                for (int j = 0; j < 8; ++j) acc[i][j] = fmaf(a[i], b[j], acc[i][j]);
        }
        __syncthreads();
    }
#pragma unroll
    for (int i = 0; i < RPT; ++i) {
        uint4 o;
        o.x = pack2(acc[i][0], acc[i][1]);
        o.y = pack2(acc[i][2], acc[i][3]);
        o.z = pack2(acc[i][4], acc[i][5]);
        o.w = pack2(acc[i][6], acc[i][7]);
        *(uint4*)(outp + (size_t)(row0 + ty * RPT + i) * DOUT + tx * 8) = o;
    }
}

// ---------------------------------------------------------------------------
// BN stats / finalize / apply  (h stored bf16)
// stats layout: [sum(DOUT) | sumsq(DOUT) | scale(DOUT) | shift(DOUT)]
// ---------------------------------------------------------------------------
template <int DOUT>
__global__ __launch_bounds__(256)
void bn_stats(const u16* __restrict__ h, float* __restrict__ stats, int total4) {
    constexpr int C4 = DOUT / 4;          // u32x2 groups per row (32 or 16)
    float s[4] = {0, 0, 0, 0}, q[4] = {0, 0, 0, 0};
    for (int idx = blockIdx.x * 256 + threadIdx.x; idx < total4; idx += gridDim.x * 256) {
        uint2 u = ((const uint2*)h)[idx];
        float v0 = bflo(u.x), v1 = bfhi(u.x), v2 = bflo(u.y), v3 = bfhi(u.y);
        s[0] += v0; q[0] += v0 * v0;
        s[1] += v1; q[1] += v1 * v1;
        s[2] += v2; q[2] += v2 * v2;
        s[3] += v3; q[3] += v3 * v3;
    }
    __shared__ float ls[256][4], lq[256][4];
#pragma unroll
    for (int j = 0; j < 4; ++j) { ls[threadIdx.x][j] = s[j]; lq[threadIdx.x][j] = q[j]; }
    __syncthreads();
    int t = threadIdx.x;
    if (t < C4) {
#pragma unroll 1
        for (int g = 1; g < 256 / C4; ++g) {
#pragma unroll
            for (int j = 0; j < 4; ++j) { s[j] += ls[t + g * C4][j]; q[j] += lq[t + g * C4][j]; }
        }
#pragma unroll
        for (int j = 0; j < 4; ++j) {
            atomicAdd(&stats[t * 4 + j], s[j]);
            atomicAdd(&stats[DOUT + t * 4 + j], q[j]);
        }
    }
}

__global__ void bn_finalize(float* __restrict__ stats, const float* __restrict__ gamma,
                            const float* __restrict__ beta, int dout, float inv_n) {
    int c = threadIdx.x;
    if (c < dout) {
        float m = stats[c] * inv_n;
        float var = stats[dout + c] * inv_n - m * m;
        float sc = rsqrtf(var + BN_EPS) * gamma[c];
        stats[2 * dout + c] = sc;
        stats[3 * dout + c] = beta[c] - m * sc;
    }
}

template <int DOUT, bool SKIP>
__global__ __launch_bounds__(256)
void bn_apply(u16* __restrict__ h, const float* __restrict__ stats,
              const u16* __restrict__ skip, int total4) {
    constexpr int C4 = DOUT / 4;
    const float* scale = stats + 2 * DOUT;
    const float* shift = stats + 3 * DOUT;
    for (int idx = blockIdx.x * 256 + threadIdx.x; idx < total4; idx += gridDim.x * 256) {
        int c4 = (idx % C4) * 4;
        uint2 u = ((const uint2*)h)[idx];
        float v0 = bflo(u.x), v1 = bfhi(u.x), v2 = bflo(u.y), v3 = bfhi(u.y);
        v0 = fmaxf(fmaf(v0, scale[c4 + 0], shift[c4 + 0]), 0.f);
        v1 = fmaxf(fmaf(v1, scale[c4 + 1], shift[c4 + 1]), 0.f);
        v2 = fmaxf(fmaf(v2, scale[c4 + 2], shift[c4 + 2]), 0.f);
        v3 = fmaxf(fmaf(v3, scale[c4 + 3], shift[c4 + 3]), 0.f);
        if (SKIP) {
            uint2 sk = ((const uint2*)skip)[idx];
            v0 += bflo(sk.x); v1 += bfhi(sk.x); v2 += bflo(sk.y); v3 += bfhi(sk.y);
        }
        uint2 o; o.x = pack2(v0, v1); o.y = pack2(v2, v3);
        ((uint2*)h)[idx] = o;
    }
}

// ---------------------------------------------------------------------------
// graph boundaries (segment_ids sorted)
// ---------------------------------------------------------------------------
__global__ void gstart_min(const int* __restrict__ seg, int* __restrict__ gstart, int n) {
    int i = blockIdx.x * 256 + threadIdx.x;
    if (i < n) atomicMin(&gstart[seg[i]], i);
}

__global__ void gstart_fix(int* __restrict__ gstart, int g_count, int n) {
    if (blockIdx.x == 0 && threadIdx.x == 0) {
        gstart[g_count] = n;
        for (int g = g_count - 1; g >= 0; --g)
            if (gstart[g] > n) gstart[g] = gstart[g + 1];
    }
}

// ---------------------------------------------------------------------------
// pooling: per-graph max/min/mean/std over h[N,64] (bf16); one wave per graph
// pooled layout: [G][4][64] fp32
// ---------------------------------------------------------------------------
__global__ __launch_bounds__(256)
void pool_kernel(const u16* __restrict__ h, const int* __restrict__ gstart,
                 float* __restrict__ pooled, int g_count) {
    int wave = threadIdx.x >> 6;
    int lane = threadIdx.x & 63;
    int g = blockIdx.x * 4 + wave;
    if (g >= g_count) return;
    int s = gstart[g], e = gstart[g + 1];
    float mx = -INFINITY, mn = INFINITY, sm = 0.f, sq = 0.f;
    for (int nidx = s; nidx < e; ++nidx) {
        float v = bf1(h[(size_t)nidx * 64 + lane]);
        mx = fmaxf(mx, v);
        mn = fminf(mn, v);
        sm += v;
        sq += v * v;
    }
    float cnt = (float)(e - s);
    float mean = sm / fmaxf(cnt, 1.f);
    float var = (sq - cnt * mean * mean) / fmaxf(cnt - 1.f, 1.f);
    float sd = sqrtf(fmaxf(var, 0.f));
    size_t base = (size_t)g * 256;
    pooled[base + 0 * 64 + lane] = mx;
    pooled[base + 1 * 64 + lane] = mn;
    pooled[base + 2 * 64 + lane] = mean;
    pooled[base + 3 * 64 + lane] = sd;
}

// agg BN stats: 4 channels, stats over G x 64 elements each; one block per channel
__global__ void agg_stats(const float* __restrict__ pooled, float* __restrict__ aggstat,
                          int g_count) {
    int ch = blockIdx.x;
    int total = g_count * 64;
    float s = 0.f, q = 0.f;
    for (int i = threadIdx.x; i < total; i += 256) {
        int g = i >> 6, f = i & 63;
        float v = pooled[(size_t)g * 256 + ch * 64 + f];
        s += v; q += v * v;
    }
    __shared__ float ls[256], lq[256];
    ls[threadIdx.x] = s; lq[threadIdx.x] = q;
    __syncthreads();
    for (int off = 128; off > 0; off >>= 1) {
        if (threadIdx.x < off) {
            ls[threadIdx.x] += ls[threadIdx.x + off];
            lq[threadIdx.x] += lq[threadIdx.x + off];
        }
        __syncthreads();
    }
    if (threadIdx.x == 0) {
        float inv = 1.f / (float)total;
        float m = ls[0] * inv;
        aggstat[ch * 2 + 0] = m;
        aggstat[ch * 2 + 1] = lq[0] * inv - m * m;
    }
}

// final head: normalize pooled, Linear(256->64), Linear(64->1). One wave per graph.
// aggW read directly from global (tiny, cache-resident). LDS use: 4 KB.
__global__ __launch_bounds__(256)
void final_kernel(const float* __restrict__ pooled, const float* __restrict__ aggstat,
                  const float* __restrict__ agg_gamma, const float* __restrict__ agg_beta,
                  const float* __restrict__ aggW, const float* __restrict__ aggb,
                  const float* __restrict__ outW, const float* __restrict__ outb,
                  float* __restrict__ out, int g_count) {
    __shared__ float sflat[4][256];
    int wave = threadIdx.x >> 6;
    int lane = threadIdx.x & 63;
    int g = blockIdx.x * 4 + wave;
    if (g < g_count) {
#pragma unroll
        for (int c = 0; c < 4; ++c) {
            float v = pooled[(size_t)g * 256 + c * 64 + lane];
            float m = aggstat[c * 2], var = aggstat[c * 2 + 1];
            v = (v - m) * rsqrtf(var + BN_EPS) * agg_gamma[c] + agg_beta[c];
            sflat[wave][c * 64 + lane] = v;
        }
    }
    __syncthreads();
    if (g < g_count) {
        float acc = aggb[lane];
        const float* wrow = aggW + lane * 256;
#pragma unroll 8
        for (int i = 0; i < 256; ++i)
            acc = fmaf(sflat[wave][i], wrow[i], acc);
        float t = acc * outW[lane];
        for (int off = 32; off > 0; off >>= 1) t += __shfl_down(t, off, 64);
        if (lane == 0) out[g] = t + outb[0];
    }
}

// ---------------------------------------------------------------------------
// host launcher
// ---------------------------------------------------------------------------
extern "C" void kernel_launch(void* const* d_in, const int* in_sizes, int n_in,
                              void* d_out, int out_size, void* d_ws, size_t ws_size,
                              hipStream_t stream) {
    const int N = N_NODES, E = N_EDGES, G = N_GRAPHS;

    const float* x           = (const float*)d_in[0];
    const int*   ei          = (const int*)d_in[1];      // [2, E]
    const int*   seg         = (const int*)d_in[2];      // [N]
    const float* conv_W      = (const float*)d_in[3];    // [5, 384, 128]
    const float* conv_W_last = (const float*)d_in[4];    // [384, 64]
    const float* bn_g        = (const float*)d_in[5];    // [5,128]
    const float* bn_b        = (const float*)d_in[6];
    const float* bn_gl       = (const float*)d_in[7];    // [64]
    const float* bn_bl       = (const float*)d_in[8];
    const float* agg_g       = (const float*)d_in[9];    // [4]
    const float* agg_bt      = (const float*)d_in[10];
    const float* aggW        = (const float*)d_in[11];   // [64,256]
    const float* aggb        = (const float*)d_in[12];   // [64]
    const float* outW        = (const float*)d_in[13];   // [1,64]
    const float* outb        = (const float*)d_in[14];   // [1]
    float* out = (float*)d_out;

    const int* esrc = ei;
    const int* edst = ei + E;

    // ---- workspace bump allocator (total ~274 MB) ----
    size_t off = 0;
    auto alloc = [&](size_t bytes) -> void* {
        void* p = (char*)d_ws + off;
        off += (bytes + 255) & ~(size_t)255;
        return p;
    };
    int*   deg_i  = (int*)alloc((size_t)N * 4);
    float* normv  = (float*)alloc((size_t)N * 4);
    int*   rowptr = (int*)alloc((size_t)(N + 1) * 4);
    int*   bsums  = (int*)alloc(128 * 4);
    int*   pos    = (int*)alloc((size_t)N * 4);
    int*   csr    = (int*)alloc((size_t)E * 4);
    int*   gstart = (int*)alloc((size_t)(G + 1) * 4);
    float* stats  = (float*)alloc(4 * 128 * 4);
    float* aggstat= (float*)alloc(8 * 4);
    float* pooled = (float*)alloc((size_t)G * 256 * 4);
    u16*   ring0  = (u16*)alloc((size_t)N * 128 * 2);
    u16*   ring1  = (u16*)alloc((size_t)N * 128 * 2);
    u16*   ring2  = (u16*)alloc((size_t)N * 128 * 2);
    u16*   p1     = (u16*)alloc((size_t)N * 128 * 2);
    u16*   p2     = (u16*)alloc((size_t)N * 128 * 2);
    u16*   ring[3] = {ring0, ring1, ring2};

    // ---- degree + norm ----
    hipMemsetAsync(deg_i, 0, (size_t)N * 4, stream);
    deg_kernel<<<(E + 255) / 256, 256, 0, stream>>>(edst, deg_i, E);
    norm_kernel<<<(N + 255) / 256, 256, 0, stream>>>(deg_i, normv, N);

    // ---- x -> bf16 (into ring2; dead before layer 2 writes it) ----
    x2bf_kernel<<<2048, 256, 0, stream>>>(x, ring2, N * 128 / 4);

    // ---- CSR build ----
    int nscan = (N + 2047) / 2048;   // 98
    scan_block_sums<<<nscan, 256, 0, stream>>>(deg_i, bsums, N);
    scan_exclusive_small<<<1, 128, 0, stream>>>(bsums, nscan);
    scan_final<<<nscan, 256, 0, stream>>>(deg_i, bsums, rowptr, N);
    copy_int_kernel<<<(N + 255) / 256, 256, 0, stream>>>(rowptr, pos, N);
    fill_csr<<<(E + 255) / 256, 256, 0, stream>>>(esrc, edst, pos, csr, E);

    // ---- graph boundaries ----
    hipMemsetAsync(gstart, 0x7f, (size_t)(G + 1) * 4, stream);
    gstart_min<<<(N + 255) / 256, 256, 0, stream>>>(seg, gstart, N);
    gstart_fix<<<1, 64, 0, stream>>>(gstart, G, N);

    // ---- layers ----
    const u16* h_in = ring2;   // x in bf16
    for (int l = 0; l < 6; ++l) {
        const int dout = (l < 5) ? 128 : 64;
        const float* W     = (l < 5) ? (conv_W + (size_t)l * 384 * 128) : conv_W_last;
        const float* gamma = (l < 5) ? (bn_g + l * 128) : bn_gl;
        const float* beta  = (l < 5) ? (bn_b + l * 128) : bn_bl;
        u16* outbuf = ring[l % 3];

        prop_kernel<<<(N + 3) / 4, 256, 0, stream>>>(h_in, normv, rowptr, csr, p1, N);
        prop_kernel<<<(N + 3) / 4, 256, 0, stream>>>(p1, normv, rowptr, csr, p2, N);

        if (dout == 128)
            gemm_cat3<128><<<N / 64, 256, 0, stream>>>(h_in, p1, p2, W, outbuf);
        else
            gemm_cat3<64><<<N / 64, 256, 0, stream>>>(h_in, p1, p2, W, outbuf);

        hipMemsetAsync(stats, 0, (size_t)2 * dout * 4, stream);
        int total4 = N * dout / 4;
        if (dout == 128)
            bn_stats<128><<<512, 256, 0, stream>>>(outbuf, stats, total4);
        else
            bn_stats<64><<<512, 256, 0, stream>>>(outbuf, stats, total4);
        bn_finalize<<<1, 128, 0, stream>>>(stats, gamma, beta, dout, 1.f / (float)N);

        bool has_skip = (l >= 2 && l < 5);
        const u16* skipb = has_skip ? ring[(l - 2) % 3] : nullptr;
        if (dout == 128) {
            if (has_skip)
                bn_apply<128, true><<<8192, 256, 0, stream>>>(outbuf, stats, skipb, total4);
            else
                bn_apply<128, false><<<8192, 256, 0, stream>>>(outbuf, stats, nullptr, total4);
        } else {
            bn_apply<64, false><<<8192, 256, 0, stream>>>(outbuf, stats, nullptr, total4);
        }
        h_in = outbuf;
    }

    // ---- pooling + head ----
    pool_kernel<<<(G + 3) / 4, 256, 0, stream>>>(ring[5 % 3], gstart, pooled, G);
    agg_stats<<<4, 256, 0, stream>>>(pooled, aggstat, G);
    final_kernel<<<(G + 3) / 4, 256, 0, stream>>>(pooled, aggstat, agg_g, agg_bt,
                                                  aggW, aggb, outW, outb, out, G);
}

// Round 3
// 3622.034 us; speedup vs baseline: 1.4509x; 1.4509x over previous
//
#include <hip/hip_runtime.h>
#include <cstddef>
#include <cstdint>

#define N_NODES  200000
#define N_EDGES  3200000
#define N_GRAPHS 2000
#define BN_EPS   1e-5f

typedef unsigned int   u32;
typedef unsigned short u16;

using short8   = __attribute__((ext_vector_type(8))) short;
using floatx16 = __attribute__((ext_vector_type(16))) float;

// ---------------------------------------------------------------------------
// bf16 helpers (raw-bit, RNE pack)
// ---------------------------------------------------------------------------
__device__ __forceinline__ float bflo(u32 v) { union {u32 i; float f;} c; c.i = v << 16; return c.f; }
__device__ __forceinline__ float bfhi(u32 v) { union {u32 i; float f;} c; c.i = v & 0xffff0000u; return c.f; }
__device__ __forceinline__ float bf1(u16 v)  { union {u32 i; float f;} c; c.i = ((u32)v) << 16; return c.f; }
__device__ __forceinline__ u32 f2bf(float f) {
    union {float f; u32 i;} c; c.f = f;
    return (c.i + 0x7fffu + ((c.i >> 16) & 1u)) >> 16;
}
__device__ __forceinline__ u32 pack2(float a, float b) { return f2bf(a) | (f2bf(b) << 16); }

// ---------------------------------------------------------------------------
// degree / norm
// ---------------------------------------------------------------------------
__global__ void deg_kernel(const int* __restrict__ dst, int* __restrict__ deg, int e) {
    int i = blockIdx.x * 256 + threadIdx.x;
    if (i < e) atomicAdd(&deg[dst[i]], 1);
}

__global__ void norm_kernel(const int* __restrict__ deg, float* __restrict__ norm, int n) {
    int i = blockIdx.x * 256 + threadIdx.x;
    if (i < n) {
        int d = deg[i];
        norm[i] = (d > 0) ? rsqrtf((float)d) : 0.f;
    }
}

// ---------------------------------------------------------------------------
// x (fp32) -> bf16
// ---------------------------------------------------------------------------
__global__ void x2bf_kernel(const float* __restrict__ x, u16* __restrict__ xb, int total4) {
    for (int i = blockIdx.x * 256 + threadIdx.x; i < total4; i += gridDim.x * 256) {
        float4 v = ((const float4*)x)[i];
        uint2 o; o.x = pack2(v.x, v.y); o.y = pack2(v.z, v.w);
        ((uint2*)xb)[i] = o;
    }
}

// ---------------------------------------------------------------------------
// W pack: fp32 W[K,DOUT] -> transposed, K-chunked, hi/lo bf16
// dst[c][n][kk] with c=k/64, kk=k%64
// ---------------------------------------------------------------------------
__global__ void wpack_kernel(const float* __restrict__ W, u16* __restrict__ whi,
                             u16* __restrict__ wlo, int K, int DOUT) {
    int tid = blockIdx.x * 256 + threadIdx.x;
    if (tid >= K * DOUT) return;
    int k = tid / DOUT, nn = tid % DOUT;
    float w = W[tid];
    u16 hi = (u16)f2bf(w);
    float rem = w - bf1(hi);
    u16 lo = (u16)f2bf(rem);
    int dst = (k >> 6) * DOUT * 64 + nn * 64 + (k & 63);
    whi[dst] = hi;
    wlo[dst] = lo;
}

// ---------------------------------------------------------------------------
// scan for CSR rowptr (chunk = 2048 per block)
// ---------------------------------------------------------------------------
__global__ void scan_block_sums(const int* __restrict__ deg, int* __restrict__ bsums, int n) {
    int base = blockIdx.x * 2048;
    int s = 0;
    for (int i = threadIdx.x; i < 2048; i += 256) {
        int idx = base + i;
        s += (idx < n) ? deg[idx] : 0;
    }
    __shared__ int ls[256];
    ls[threadIdx.x] = s;
    __syncthreads();
    for (int off = 128; off > 0; off >>= 1) {
        if (threadIdx.x < off) ls[threadIdx.x] += ls[threadIdx.x + off];
        __syncthreads();
    }
    if (threadIdx.x == 0) bsums[blockIdx.x] = ls[0];
}

__global__ void scan_exclusive_small(int* __restrict__ bsums, int nb) {
    __shared__ int ls[128];
    int t = threadIdx.x;
    int v = (t < nb) ? bsums[t] : 0;
    ls[t] = v;
    __syncthreads();
    for (int off = 1; off < 128; off <<= 1) {
        int add = (t >= off) ? ls[t - off] : 0;
        __syncthreads();
        ls[t] += add;
        __syncthreads();
    }
    if (t < nb) bsums[t] = ls[t] - v;   // exclusive
}

__global__ void scan_final(const int* __restrict__ deg, const int* __restrict__ bsums,
                           int* __restrict__ rowptr, int n) {
    int base = blockIdx.x * 2048;
    int t = threadIdx.x;
    int i0 = base + t * 8;
    int vals[8];
    int s = 0;
#pragma unroll
    for (int j = 0; j < 8; ++j) {
        int idx = i0 + j;
        vals[j] = (idx < n) ? deg[idx] : 0;
        s += vals[j];
    }
    __shared__ int ls[256];
    ls[t] = s;
    __syncthreads();
    for (int off = 1; off < 256; off <<= 1) {
        int add = (t >= off) ? ls[t - off] : 0;
        __syncthreads();
        ls[t] += add;
        __syncthreads();
    }
    int run = bsums[blockIdx.x] + ls[t] - s;
#pragma unroll
    for (int j = 0; j < 8; ++j) {
        int idx = i0 + j;
        if (idx < n) rowptr[idx] = run;
        run += vals[j];
    }
    if (n - 1 >= i0 && n - 1 < i0 + 8) rowptr[n] = run;
}

__global__ void copy_int_kernel(const int* __restrict__ src, int* __restrict__ dst, int n) {
    int i = blockIdx.x * 256 + threadIdx.x;
    if (i < n) dst[i] = src[i];
}

__global__ void fill_csr(const int* __restrict__ esrc, const int* __restrict__ edst,
                         int* __restrict__ pos, int* __restrict__ csr, int e) {
    int i = blockIdx.x * 256 + threadIdx.x;
    if (i < e) {
        int d = edst[i];
        int slot = atomicAdd(&pos[d], 1);
        csr[slot] = esrc[i];
    }
}

// ---------------------------------------------------------------------------
// prop: p[dst] = norm[dst] * sum_{src in N(dst)} norm[src] * h[src]   (d = 128)
// bf16 in / bf16 out; one wave per node, lane handles 2 features; unroll 4
// ---------------------------------------------------------------------------
__global__ __launch_bounds__(256)
void prop_kernel(const u16* __restrict__ hin, const float* __restrict__ norm,
                 const int* __restrict__ rowptr, const int* __restrict__ csr,
                 u16* __restrict__ pout, int n) {
    int wave = threadIdx.x >> 6;
    int lane = threadIdx.x & 63;
    int node = blockIdx.x * 4 + wave;
    if (node >= n) return;
    int s = rowptr[node], e = rowptr[node + 1];
    float ax = 0.f, ay = 0.f;
    int i = s;
    for (; i + 3 < e; i += 4) {
        int s0 = csr[i], s1 = csr[i + 1], s2 = csr[i + 2], s3 = csr[i + 3];
        float n0 = norm[s0], n1 = norm[s1], n2 = norm[s2], n3 = norm[s3];
        u32 v0 = ((const u32*)(hin + (size_t)s0 * 128))[lane];
        u32 v1 = ((const u32*)(hin + (size_t)s1 * 128))[lane];
        u32 v2 = ((const u32*)(hin + (size_t)s2 * 128))[lane];
        u32 v3 = ((const u32*)(hin + (size_t)s3 * 128))[lane];
        ax += bflo(v0) * n0 + bflo(v1) * n1 + bflo(v2) * n2 + bflo(v3) * n3;
        ay += bfhi(v0) * n0 + bfhi(v1) * n1 + bfhi(v2) * n2 + bfhi(v3) * n3;
    }
    for (; i < e; ++i) {
        int s0 = csr[i];
        float n0 = norm[s0];
        u32 v0 = ((const u32*)(hin + (size_t)s0 * 128))[lane];
        ax += bflo(v0) * n0;
        ay += bfhi(v0) * n0;
    }
    float nd = norm[node];
    ((u32*)(pout + (size_t)node * 128))[lane] = pack2(ax * nd, ay * nd);
}

// ---------------------------------------------------------------------------
// MFMA GEMM: out[N,DOUT](bf16) = [A0|A1|A2](bf16, K=384) @ (Whi+Wlo)
// Block: 128 rows x DOUT cols, 4 waves. Wave: 64 x (TJ*32), 2 x TJ of 32x32.
// K-chunk BK=64 staged in LDS with 16B-chunk XOR swizzle.
// Whi/Wlo pre-packed: [chunk][n][64] bf16 (transposed).
// ---------------------------------------------------------------------------
template <int DOUT>
__global__ __launch_bounds__(256)
void gemm_mfma(const u16* __restrict__ A0, const u16* __restrict__ A1,
               const u16* __restrict__ A2, const u16* __restrict__ whi,
               const u16* __restrict__ wlo, u16* __restrict__ outp, int n) {
    constexpr int TJ = DOUT / 64;            // 2 (dout=128) or 1 (dout=64)
    constexpr int BELEMS = DOUT * 64;        // B chunk elems
    __shared__ u16 As[128 * 64];
    __shared__ u16 Bh[BELEMS];
    __shared__ u16 Bl[BELEMS];

    const int tid  = threadIdx.x;
    const int wave = tid >> 6;
    const int lane = tid & 63;
    const int wrow = wave >> 1;              // 0..1
    const int wcol = wave & 1;               // 0..1
    const int row0 = blockIdx.x * 128;
    const int m    = lane & 31;
    const int half = lane >> 5;

    const u16* mats[3] = {A0, A1, A2};

    floatx16 acc[2][TJ];
#pragma unroll
    for (int ti = 0; ti < 2; ++ti)
#pragma unroll
        for (int tj = 0; tj < TJ; ++tj)
#pragma unroll
            for (int r = 0; r < 16; ++r) acc[ti][tj][r] = 0.f;

    for (int c = 0; c < 6; ++c) {
        const u16* M = mats[c >> 1];
        const int kloc = (c & 1) * 64;
        // ---- stage A: 8 rows per wave-instr, 4 iters per wave ----
#pragma unroll
        for (int it = 0; it < 4; ++it) {
            int rib  = wave * 32 + it * 8 + (lane >> 3);
            int grow = row0 + rib;
            if (grow >= n) grow = n - 1;
            uint4 v = *(const uint4*)(M + (size_t)grow * 128 + kloc + (lane & 7) * 8);
            int cc = (lane & 7) ^ (rib & 7);
            *(uint4*)&As[rib * 64 + cc * 8] = v;
        }
        // ---- stage B hi/lo (packed contiguous per chunk) ----
        {
            const int cbase = c * BELEMS;
#pragma unroll
            for (int j = 0; j < BELEMS / 2048; ++j) {
                int idx  = tid + j * 256;        // uint4 index
                int nrow = idx >> 3, seg = idx & 7;
                int dcc  = seg ^ (nrow & 7);
                *(uint4*)&Bh[nrow * 64 + dcc * 8] =
                    *(const uint4*)(whi + cbase + idx * 8);
                *(uint4*)&Bl[nrow * 64 + dcc * 8] =
                    *(const uint4*)(wlo + cbase + idx * 8);
            }
        }
        __syncthreads();
        // ---- 4 k-steps of 16 ----
#pragma unroll
        for (int s = 0; s < 4; ++s) {
            const int cc = s * 2 + half;
            short8 a[2], bhf[TJ], blf[TJ];
#pragma unroll
            for (int ti = 0; ti < 2; ++ti) {
                int r = wrow * 64 + ti * 32 + m;
                a[ti] = *(const short8*)&As[r * 64 + ((cc ^ (r & 7)) * 8)];
            }
#pragma unroll
            for (int tj = 0; tj < TJ; ++tj) {
                int rr = wcol * TJ * 32 + tj * 32 + m;
                int off = rr * 64 + ((cc ^ (rr & 7)) * 8);
                bhf[tj] = *(const short8*)&Bh[off];
                blf[tj] = *(const short8*)&Bl[off];
            }
#pragma unroll
            for (int ti = 0; ti < 2; ++ti)
#pragma unroll
                for (int tj = 0; tj < TJ; ++tj) {
                    acc[ti][tj] = __builtin_amdgcn_mfma_f32_32x32x16_bf16(
                        a[ti], bhf[tj], acc[ti][tj], 0, 0, 0);
                    acc[ti][tj] = __builtin_amdgcn_mfma_f32_32x32x16_bf16(
                        a[ti], blf[tj], acc[ti][tj], 0, 0, 0);
                }
        }
        __syncthreads();
    }

    // ---- epilogue: C layout col=lane&31, row=(r&3)+8*(r>>2)+4*half ----
#pragma unroll
    for (int ti = 0; ti < 2; ++ti)
#pragma unroll
        for (int tj = 0; tj < TJ; ++tj) {
            int gcol = (wcol * TJ + tj) * 32 + m;
#pragma unroll
            for (int r = 0; r < 16; ++r) {
                int grow = row0 + wrow * 64 + ti * 32 + (r & 3) + 8 * (r >> 2) + 4 * half;
                if (grow < n)
                    outp[(size_t)grow * DOUT + gcol] = (u16)f2bf(acc[ti][tj][r]);
            }
        }
}

// ---------------------------------------------------------------------------
// BN stats / finalize / apply  (h stored bf16)
// stats layout: [sum(DOUT) | sumsq(DOUT) | scale(DOUT) | shift(DOUT)]
// ---------------------------------------------------------------------------
template <int DOUT>
__global__ __launch_bounds__(256)
void bn_stats(const u16* __restrict__ h, float* __restrict__ stats, int total4) {
    constexpr int C4 = DOUT / 4;
    float s[4] = {0, 0, 0, 0}, q[4] = {0, 0, 0, 0};
    for (int idx = blockIdx.x * 256 + threadIdx.x; idx < total4; idx += gridDim.x * 256) {
        uint2 u = ((const uint2*)h)[idx];
        float v0 = bflo(u.x), v1 = bfhi(u.x), v2 = bflo(u.y), v3 = bfhi(u.y);
        s[0] += v0; q[0] += v0 * v0;
        s[1] += v1; q[1] += v1 * v1;
        s[2] += v2; q[2] += v2 * v2;
        s[3] += v3; q[3] += v3 * v3;
    }
    __shared__ float ls[256][4], lq[256][4];
#pragma unroll
    for (int j = 0; j < 4; ++j) { ls[threadIdx.x][j] = s[j]; lq[threadIdx.x][j] = q[j]; }
    __syncthreads();
    int t = threadIdx.x;
    if (t < C4) {
#pragma unroll 1
        for (int g = 1; g < 256 / C4; ++g) {
#pragma unroll
            for (int j = 0; j < 4; ++j) { s[j] += ls[t + g * C4][j]; q[j] += lq[t + g * C4][j]; }
        }
#pragma unroll
        for (int j = 0; j < 4; ++j) {
            atomicAdd(&stats[t * 4 + j], s[j]);
            atomicAdd(&stats[DOUT + t * 4 + j], q[j]);
        }
    }
}

__global__ void bn_finalize(float* __restrict__ stats, const float* __restrict__ gamma,
                            const float* __restrict__ beta, int dout, float inv_n) {
    int c = threadIdx.x;
    if (c < dout) {
        float m = stats[c] * inv_n;
        float var = stats[dout + c] * inv_n - m * m;
        float sc = rsqrtf(var + BN_EPS) * gamma[c];
        stats[2 * dout + c] = sc;
        stats[3 * dout + c] = beta[c] - m * sc;
    }
}

template <int DOUT, bool SKIP>
__global__ __launch_bounds__(256)
void bn_apply(u16* __restrict__ h, const float* __restrict__ stats,
              const u16* __restrict__ skip, int total4) {
    constexpr int C4 = DOUT / 4;
    const float* scale = stats + 2 * DOUT;
    const float* shift = stats + 3 * DOUT;
    for (int idx = blockIdx.x * 256 + threadIdx.x; idx < total4; idx += gridDim.x * 256) {
        int c4 = (idx % C4) * 4;
        uint2 u = ((const uint2*)h)[idx];
        float v0 = bflo(u.x), v1 = bfhi(u.x), v2 = bflo(u.y), v3 = bfhi(u.y);
        v0 = fmaxf(fmaf(v0, scale[c4 + 0], shift[c4 + 0]), 0.f);
        v1 = fmaxf(fmaf(v1, scale[c4 + 1], shift[c4 + 1]), 0.f);
        v2 = fmaxf(fmaf(v2, scale[c4 + 2], shift[c4 + 2]), 0.f);
        v3 = fmaxf(fmaf(v3, scale[c4 + 3], shift[c4 + 3]), 0.f);
        if (SKIP) {
            uint2 sk = ((const uint2*)skip)[idx];
            v0 += bflo(sk.x); v1 += bfhi(sk.x); v2 += bflo(sk.y); v3 += bfhi(sk.y);
        }
        uint2 o; o.x = pack2(v0, v1); o.y = pack2(v2, v3);
        ((uint2*)h)[idx] = o;
    }
}

// ---------------------------------------------------------------------------
// graph boundaries (segment_ids sorted)
// ---------------------------------------------------------------------------
__global__ void gstart_min(const int* __restrict__ seg, int* __restrict__ gstart, int n) {
    int i = blockIdx.x * 256 + threadIdx.x;
    if (i < n) atomicMin(&gstart[seg[i]], i);
}

__global__ void gstart_fix(int* __restrict__ gstart, int g_count, int n) {
    if (blockIdx.x == 0 && threadIdx.x == 0) {
        gstart[g_count] = n;
        for (int g = g_count - 1; g >= 0; --g)
            if (gstart[g] > n) gstart[g] = gstart[g + 1];
    }
}

// ---------------------------------------------------------------------------
// pooling: per-graph max/min/mean/std over h[N,64] (bf16); one wave per graph
// ---------------------------------------------------------------------------
__global__ __launch_bounds__(256)
void pool_kernel(const u16* __restrict__ h, const int* __restrict__ gstart,
                 float* __restrict__ pooled, int g_count) {
    int wave = threadIdx.x >> 6;
    int lane = threadIdx.x & 63;
    int g = blockIdx.x * 4 + wave;
    if (g >= g_count) return;
    int s = gstart[g], e = gstart[g + 1];
    float mx = -INFINITY, mn = INFINITY, sm = 0.f, sq = 0.f;
    for (int nidx = s; nidx < e; ++nidx) {
        float v = bf1(h[(size_t)nidx * 64 + lane]);
        mx = fmaxf(mx, v);
        mn = fminf(mn, v);
        sm += v;
        sq += v * v;
    }
    float cnt = (float)(e - s);
    float mean = sm / fmaxf(cnt, 1.f);
    float var = (sq - cnt * mean * mean) / fmaxf(cnt - 1.f, 1.f);
    float sd = sqrtf(fmaxf(var, 0.f));
    size_t base = (size_t)g * 256;
    pooled[base + 0 * 64 + lane] = mx;
    pooled[base + 1 * 64 + lane] = mn;
    pooled[base + 2 * 64 + lane] = mean;
    pooled[base + 3 * 64 + lane] = sd;
}

__global__ void agg_stats(const float* __restrict__ pooled, float* __restrict__ aggstat,
                          int g_count) {
    int ch = blockIdx.x;
    int total = g_count * 64;
    float s = 0.f, q = 0.f;
    for (int i = threadIdx.x; i < total; i += 256) {
        int g = i >> 6, f = i & 63;
        float v = pooled[(size_t)g * 256 + ch * 64 + f];
        s += v; q += v * v;
    }
    __shared__ float ls[256], lq[256];
    ls[threadIdx.x] = s; lq[threadIdx.x] = q;
    __syncthreads();
    for (int off = 128; off > 0; off >>= 1) {
        if (threadIdx.x < off) {
            ls[threadIdx.x] += ls[threadIdx.x + off];
            lq[threadIdx.x] += lq[threadIdx.x + off];
        }
        __syncthreads();
    }
    if (threadIdx.x == 0) {
        float inv = 1.f / (float)total;
        float m = ls[0] * inv;
        aggstat[ch * 2 + 0] = m;
        aggstat[ch * 2 + 1] = lq[0] * inv - m * m;
    }
}

__global__ __launch_bounds__(256)
void final_kernel(const float* __restrict__ pooled, const float* __restrict__ aggstat,
                  const float* __restrict__ agg_gamma, const float* __restrict__ agg_beta,
                  const float* __restrict__ aggW, const float* __restrict__ aggb,
                  const float* __restrict__ outW, const float* __restrict__ outb,
                  float* __restrict__ out, int g_count) {
    __shared__ float sflat[4][256];
    int wave = threadIdx.x >> 6;
    int lane = threadIdx.x & 63;
    int g = blockIdx.x * 4 + wave;
    if (g < g_count) {
#pragma unroll
        for (int c = 0; c < 4; ++c) {
            float v = pooled[(size_t)g * 256 + c * 64 + lane];
            float m = aggstat[c * 2], var = aggstat[c * 2 + 1];
            v = (v - m) * rsqrtf(var + BN_EPS) * agg_gamma[c] + agg_beta[c];
            sflat[wave][c * 64 + lane] = v;
        }
    }
    __syncthreads();
    if (g < g_count) {
        float acc = aggb[lane];
        const float* wrow = aggW + lane * 256;
#pragma unroll 8
        for (int i = 0; i < 256; ++i)
            acc = fmaf(sflat[wave][i], wrow[i], acc);
        float t = acc * outW[lane];
        for (int off = 32; off > 0; off >>= 1) t += __shfl_down(t, off, 64);
        if (lane == 0) out[g] = t + outb[0];
    }
}

// ---------------------------------------------------------------------------
// host launcher
// ---------------------------------------------------------------------------
extern "C" void kernel_launch(void* const* d_in, const int* in_sizes, int n_in,
                              void* d_out, int out_size, void* d_ws, size_t ws_size,
                              hipStream_t stream) {
    const int N = N_NODES, E = N_EDGES, G = N_GRAPHS;

    const float* x           = (const float*)d_in[0];
    const int*   ei          = (const int*)d_in[1];
    const int*   seg         = (const int*)d_in[2];
    const float* conv_W      = (const float*)d_in[3];
    const float* conv_W_last = (const float*)d_in[4];
    const float* bn_g        = (const float*)d_in[5];
    const float* bn_b        = (const float*)d_in[6];
    const float* bn_gl       = (const float*)d_in[7];
    const float* bn_bl       = (const float*)d_in[8];
    const float* agg_g       = (const float*)d_in[9];
    const float* agg_bt      = (const float*)d_in[10];
    const float* aggW        = (const float*)d_in[11];
    const float* aggb        = (const float*)d_in[12];
    const float* outW        = (const float*)d_in[13];
    const float* outb        = (const float*)d_in[14];
    float* out = (float*)d_out;

    const int* esrc = ei;
    const int* edst = ei + E;

    size_t off = 0;
    auto alloc = [&](size_t bytes) -> void* {
        void* p = (char*)d_ws + off;
        off += (bytes + 255) & ~(size_t)255;
        return p;
    };
    int*   deg_i  = (int*)alloc((size_t)N * 4);
    float* normv  = (float*)alloc((size_t)N * 4);
    int*   rowptr = (int*)alloc((size_t)(N + 1) * 4);
    int*   bsums  = (int*)alloc(128 * 4);
    int*   pos    = (int*)alloc((size_t)N * 4);
    int*   csr    = (int*)alloc((size_t)E * 4);
    int*   gstart = (int*)alloc((size_t)(G + 1) * 4);
    float* stats  = (float*)alloc(4 * 128 * 4);
    float* aggstat= (float*)alloc(8 * 4);
    float* pooled = (float*)alloc((size_t)G * 256 * 4);
    // packed W: 5 layers of [6][128][64] + 1 of [6][64][64]
    const size_t WPACK = 5 * 384 * 128 + 384 * 64;
    u16*   whip   = (u16*)alloc(WPACK * 2);
    u16*   wlop   = (u16*)alloc(WPACK * 2);
    u16*   ring0  = (u16*)alloc((size_t)N * 128 * 2);
    u16*   ring1  = (u16*)alloc((size_t)N * 128 * 2);
    u16*   ring2  = (u16*)alloc((size_t)N * 128 * 2);
    u16*   p1     = (u16*)alloc((size_t)N * 128 * 2);
    u16*   p2     = (u16*)alloc((size_t)N * 128 * 2);
    u16*   ring[3] = {ring0, ring1, ring2};

    // ---- degree + norm ----
    hipMemsetAsync(deg_i, 0, (size_t)N * 4, stream);
    deg_kernel<<<(E + 255) / 256, 256, 0, stream>>>(edst, deg_i, E);
    norm_kernel<<<(N + 255) / 256, 256, 0, stream>>>(deg_i, normv, N);

    // ---- x -> bf16 (into ring2; dead before layer 2 writes it) ----
    x2bf_kernel<<<2048, 256, 0, stream>>>(x, ring2, N * 128 / 4);

    // ---- W pack (hi/lo, transposed, chunked) ----
    for (int l = 0; l < 5; ++l)
        wpack_kernel<<<(384 * 128 + 255) / 256, 256, 0, stream>>>(
            conv_W + (size_t)l * 384 * 128, whip + (size_t)l * 384 * 128,
            wlop + (size_t)l * 384 * 128, 384, 128);
    wpack_kernel<<<(384 * 64 + 255) / 256, 256, 0, stream>>>(
        conv_W_last, whip + (size_t)5 * 384 * 128, wlop + (size_t)5 * 384 * 128, 384, 64);

    // ---- CSR build ----
    int nscan = (N + 2047) / 2048;
    scan_block_sums<<<nscan, 256, 0, stream>>>(deg_i, bsums, N);
    scan_exclusive_small<<<1, 128, 0, stream>>>(bsums, nscan);
    scan_final<<<nscan, 256, 0, stream>>>(deg_i, bsums, rowptr, N);
    copy_int_kernel<<<(N + 255) / 256, 256, 0, stream>>>(rowptr, pos, N);
    fill_csr<<<(E + 255) / 256, 256, 0, stream>>>(esrc, edst, pos, csr, E);

    // ---- graph boundaries ----
    hipMemsetAsync(gstart, 0x7f, (size_t)(G + 1) * 4, stream);
    gstart_min<<<(N + 255) / 256, 256, 0, stream>>>(seg, gstart, N);
    gstart_fix<<<1, 64, 0, stream>>>(gstart, G, N);

    // ---- layers ----
    const u16* h_in = ring2;
    const int gemm_grid = (N + 127) / 128;
    for (int l = 0; l < 6; ++l) {
        const int dout = (l < 5) ? 128 : 64;
        const u16* whi = whip + (size_t)((l < 5) ? l * 384 * 128 : 5 * 384 * 128);
        const u16* wlo = wlop + (size_t)((l < 5) ? l * 384 * 128 : 5 * 384 * 128);
        const float* gamma = (l < 5) ? (bn_g + l * 128) : bn_gl;
        const float* beta  = (l < 5) ? (bn_b + l * 128) : bn_bl;
        u16* outbuf = ring[l % 3];

        prop_kernel<<<(N + 3) / 4, 256, 0, stream>>>(h_in, normv, rowptr, csr, p1, N);
        prop_kernel<<<(N + 3) / 4, 256, 0, stream>>>(p1, normv, rowptr, csr, p2, N);

        if (dout == 128)
            gemm_mfma<128><<<gemm_grid, 256, 0, stream>>>(h_in, p1, p2, whi, wlo, outbuf, N);
        else
            gemm_mfma<64><<<gemm_grid, 256, 0, stream>>>(h_in, p1, p2, whi, wlo, outbuf, N);

        hipMemsetAsync(stats, 0, (size_t)2 * dout * 4, stream);
        int total4 = N * dout / 4;
        if (dout == 128)
            bn_stats<128><<<512, 256, 0, stream>>>(outbuf, stats, total4);
        else
            bn_stats<64><<<512, 256, 0, stream>>>(outbuf, stats, total4);
        bn_finalize<<<1, 128, 0, stream>>>(stats, gamma, beta, dout, 1.f / (float)N);

        bool has_skip = (l >= 2 && l < 5);
        const u16* skipb = has_skip ? ring[(l - 2) % 3] : nullptr;
        if (dout == 128) {
            if (has_skip)
                bn_apply<128, true><<<8192, 256, 0, stream>>>(outbuf, stats, skipb, total4);
            else
                bn_apply<128, false><<<8192, 256, 0, stream>>>(outbuf, stats, nullptr, total4);
        } else {
            bn_apply<64, false><<<8192, 256, 0, stream>>>(outbuf, stats, nullptr, total4);
        }
        h_in = outbuf;
    }

    // ---- pooling + head ----
    pool_kernel<<<(G + 3) / 4, 256, 0, stream>>>(ring[5 % 3], gstart, pooled, G);
    agg_stats<<<4, 256, 0, stream>>>(pooled, aggstat, G);
    final_kernel<<<(G + 3) / 4, 256, 0, stream>>>(pooled, aggstat, agg_g, agg_bt,
                                                  aggW, aggb, outW, outb, out, G);
}

// Round 4
// 3042.259 us; speedup vs baseline: 1.7274x; 1.1906x over previous
//
#include <hip/hip_runtime.h>
#include <cstddef>
#include <cstdint>

#define N_NODES  200000
#define N_EDGES  3200000
#define N_GRAPHS 2000
#define BN_EPS   1e-5f

typedef unsigned int   u32;
typedef unsigned short u16;

using short8   = __attribute__((ext_vector_type(8))) short;
using floatx16 = __attribute__((ext_vector_type(16))) float;

// ---------------------------------------------------------------------------
// bf16 helpers (raw-bit, RNE pack)
// ---------------------------------------------------------------------------
__device__ __forceinline__ float bflo(u32 v) { union {u32 i; float f;} c; c.i = v << 16; return c.f; }
__device__ __forceinline__ float bfhi(u32 v) { union {u32 i; float f;} c; c.i = v & 0xffff0000u; return c.f; }
__device__ __forceinline__ float bf1(u16 v)  { union {u32 i; float f;} c; c.i = ((u32)v) << 16; return c.f; }
__device__ __forceinline__ u32 f2bf(float f) {
    union {float f; u32 i;} c; c.f = f;
    return (c.i + 0x7fffu + ((c.i >> 16) & 1u)) >> 16;
}
__device__ __forceinline__ u32 pack2(float a, float b) { return f2bf(a) | (f2bf(b) << 16); }

// ---------------------------------------------------------------------------
// degree / norm
// ---------------------------------------------------------------------------
__global__ void deg_kernel(const int* __restrict__ dst, int* __restrict__ deg, int e) {
    int i = blockIdx.x * 256 + threadIdx.x;
    if (i < e) atomicAdd(&deg[dst[i]], 1);
}

__global__ void norm_kernel(const int* __restrict__ deg, float* __restrict__ norm, int n) {
    int i = blockIdx.x * 256 + threadIdx.x;
    if (i < n) {
        int d = deg[i];
        norm[i] = (d > 0) ? rsqrtf((float)d) : 0.f;
    }
}

// ---------------------------------------------------------------------------
// x (fp32) -> bf16
// ---------------------------------------------------------------------------
__global__ void x2bf_kernel(const float* __restrict__ x, u16* __restrict__ xb, int total4) {
    for (int i = blockIdx.x * 256 + threadIdx.x; i < total4; i += gridDim.x * 256) {
        float4 v = ((const float4*)x)[i];
        uint2 o; o.x = pack2(v.x, v.y); o.y = pack2(v.z, v.w);
        ((uint2*)xb)[i] = o;
    }
}

// ---------------------------------------------------------------------------
// W pack: fp32 W[K,DOUT] -> transposed, K-chunked, hi/lo bf16
// dst[c][n][kk] with c=k/64, kk=k%64
// ---------------------------------------------------------------------------
__global__ void wpack_kernel(const float* __restrict__ W, u16* __restrict__ whi,
                             u16* __restrict__ wlo, int K, int DOUT) {
    int tid = blockIdx.x * 256 + threadIdx.x;
    if (tid >= K * DOUT) return;
    int k = tid / DOUT, nn = tid % DOUT;
    float w = W[tid];
    u16 hi = (u16)f2bf(w);
    float rem = w - bf1(hi);
    u16 lo = (u16)f2bf(rem);
    int dst = (k >> 6) * DOUT * 64 + nn * 64 + (k & 63);
    whi[dst] = hi;
    wlo[dst] = lo;
}

// ---------------------------------------------------------------------------
// scan for CSR rowptr (chunk = 2048 per block)
// ---------------------------------------------------------------------------
__global__ void scan_block_sums(const int* __restrict__ deg, int* __restrict__ bsums, int n) {
    int base = blockIdx.x * 2048;
    int s = 0;
    for (int i = threadIdx.x; i < 2048; i += 256) {
        int idx = base + i;
        s += (idx < n) ? deg[idx] : 0;
    }
    __shared__ int ls[256];
    ls[threadIdx.x] = s;
    __syncthreads();
    for (int off = 128; off > 0; off >>= 1) {
        if (threadIdx.x < off) ls[threadIdx.x] += ls[threadIdx.x + off];
        __syncthreads();
    }
    if (threadIdx.x == 0) bsums[blockIdx.x] = ls[0];
}

__global__ void scan_exclusive_small(int* __restrict__ bsums, int nb) {
    __shared__ int ls[128];
    int t = threadIdx.x;
    int v = (t < nb) ? bsums[t] : 0;
    ls[t] = v;
    __syncthreads();
    for (int off = 1; off < 128; off <<= 1) {
        int add = (t >= off) ? ls[t - off] : 0;
        __syncthreads();
        ls[t] += add;
        __syncthreads();
    }
    if (t < nb) bsums[t] = ls[t] - v;   // exclusive
}

__global__ void scan_final(const int* __restrict__ deg, const int* __restrict__ bsums,
                           int* __restrict__ rowptr, int n) {
    int base = blockIdx.x * 2048;
    int t = threadIdx.x;
    int i0 = base + t * 8;
    int vals[8];
    int s = 0;
#pragma unroll
    for (int j = 0; j < 8; ++j) {
        int idx = i0 + j;
        vals[j] = (idx < n) ? deg[idx] : 0;
        s += vals[j];
    }
    __shared__ int ls[256];
    ls[t] = s;
    __syncthreads();
    for (int off = 1; off < 256; off <<= 1) {
        int add = (t >= off) ? ls[t - off] : 0;
        __syncthreads();
        ls[t] += add;
        __syncthreads();
    }
    int run = bsums[blockIdx.x] + ls[t] - s;
#pragma unroll
    for (int j = 0; j < 8; ++j) {
        int idx = i0 + j;
        if (idx < n) rowptr[idx] = run;
        run += vals[j];
    }
    if (n - 1 >= i0 && n - 1 < i0 + 8) rowptr[n] = run;
}

__global__ void copy_int_kernel(const int* __restrict__ src, int* __restrict__ dst, int n) {
    int i = blockIdx.x * 256 + threadIdx.x;
    if (i < n) dst[i] = src[i];
}

__global__ void fill_csr(const int* __restrict__ esrc, const int* __restrict__ edst,
                         int* __restrict__ pos, int* __restrict__ csr, int e) {
    int i = blockIdx.x * 256 + threadIdx.x;
    if (i < e) {
        int d = edst[i];
        int slot = atomicAdd(&pos[d], 1);
        csr[slot] = esrc[i];
    }
}

// ---------------------------------------------------------------------------
// prop: p[dst] = norm[dst] * sum_{src in N(dst)} norm[src] * h[src]   (d = 128)
// Quarter-wave gather: wave = 1 node, lane = quarter*16 + fgroup.
// Each lane loads uint4 (8 bf16); 16 lanes cover a 256B row; 4 edges per
// wave-instruction. Cross-quarter reduce via shfl at the end.
// ---------------------------------------------------------------------------
__global__ __launch_bounds__(256)
void prop_kernel(const u16* __restrict__ hin, const float* __restrict__ norm,
                 const int* __restrict__ rowptr, const int* __restrict__ csr,
                 u16* __restrict__ pout, int n) {
    int wave = threadIdx.x >> 6;
    int lane = threadIdx.x & 63;
    int node = blockIdx.x * 4 + wave;
    if (node >= n) return;
    const int q = lane >> 4;            // quarter 0..3
    const int f = (lane & 15) * 8;      // feature offset (bf16 units)
    int s = rowptr[node], e = rowptr[node + 1];
    float a0 = 0, a1 = 0, a2 = 0, a3 = 0, a4 = 0, a5 = 0, a6 = 0, a7 = 0;
    int i = s + q;
    for (; i + 4 < e; i += 8) {
        int sn0 = csr[i], sn1 = csr[i + 4];
        float nw0 = norm[sn0], nw1 = norm[sn1];
        uint4 v0 = *(const uint4*)(hin + (size_t)sn0 * 128 + f);
        uint4 v1 = *(const uint4*)(hin + (size_t)sn1 * 128 + f);
        a0 += bflo(v0.x) * nw0 + bflo(v1.x) * nw1;
        a1 += bfhi(v0.x) * nw0 + bfhi(v1.x) * nw1;
        a2 += bflo(v0.y) * nw0 + bflo(v1.y) * nw1;
        a3 += bfhi(v0.y) * nw0 + bfhi(v1.y) * nw1;
        a4 += bflo(v0.z) * nw0 + bflo(v1.z) * nw1;
        a5 += bfhi(v0.z) * nw0 + bfhi(v1.z) * nw1;
        a6 += bflo(v0.w) * nw0 + bflo(v1.w) * nw1;
        a7 += bfhi(v0.w) * nw0 + bfhi(v1.w) * nw1;
    }
    if (i < e) {
        int sn0 = csr[i];
        float nw0 = norm[sn0];
        uint4 v0 = *(const uint4*)(hin + (size_t)sn0 * 128 + f);
        a0 += bflo(v0.x) * nw0; a1 += bfhi(v0.x) * nw0;
        a2 += bflo(v0.y) * nw0; a3 += bfhi(v0.y) * nw0;
        a4 += bflo(v0.z) * nw0; a5 += bfhi(v0.z) * nw0;
        a6 += bflo(v0.w) * nw0; a7 += bfhi(v0.w) * nw0;
    }
    // reduce quarters: lanes f, f+16, f+32, f+48 hold partial sums of same feats
    a0 += __shfl_down(a0, 32, 64); a1 += __shfl_down(a1, 32, 64);
    a2 += __shfl_down(a2, 32, 64); a3 += __shfl_down(a3, 32, 64);
    a4 += __shfl_down(a4, 32, 64); a5 += __shfl_down(a5, 32, 64);
    a6 += __shfl_down(a6, 32, 64); a7 += __shfl_down(a7, 32, 64);
    a0 += __shfl_down(a0, 16, 64); a1 += __shfl_down(a1, 16, 64);
    a2 += __shfl_down(a2, 16, 64); a3 += __shfl_down(a3, 16, 64);
    a4 += __shfl_down(a4, 16, 64); a5 += __shfl_down(a5, 16, 64);
    a6 += __shfl_down(a6, 16, 64); a7 += __shfl_down(a7, 16, 64);
    if (q == 0) {
        float nd = norm[node];
        uint4 o;
        o.x = pack2(a0 * nd, a1 * nd);
        o.y = pack2(a2 * nd, a3 * nd);
        o.z = pack2(a4 * nd, a5 * nd);
        o.w = pack2(a6 * nd, a7 * nd);
        *(uint4*)(pout + (size_t)node * 128 + f) = o;
    }
}

// ---------------------------------------------------------------------------
// MFMA GEMM + fused BN stats: out = [A0|A1|A2](bf16,K=384) @ (Whi+Wlo)
// Block: 128 x DOUT, 4 waves (2x2), wave = 64 x (TJ*32) of 32x32 tiles.
// Epilogue: store bf16 C + per-column sum/sumsq -> LDS -> global atomics.
// ---------------------------------------------------------------------------
template <int DOUT>
__global__ __launch_bounds__(256)
void gemm_mfma(const u16* __restrict__ A0, const u16* __restrict__ A1,
               const u16* __restrict__ A2, const u16* __restrict__ whi,
               const u16* __restrict__ wlo, u16* __restrict__ outp,
               float* __restrict__ gstats, int n) {
    constexpr int TJ = DOUT / 64;
    constexpr int BELEMS = DOUT * 64;
    __shared__ u16 As[128 * 64];
    __shared__ u16 Bh[BELEMS];
    __shared__ u16 Bl[BELEMS];
    __shared__ float col_s[DOUT];
    __shared__ float col_q[DOUT];

    const int tid  = threadIdx.x;
    const int wave = tid >> 6;
    const int lane = tid & 63;
    const int wrow = wave >> 1;
    const int wcol = wave & 1;
    const int row0 = blockIdx.x * 128;
    const int m    = lane & 31;
    const int half = lane >> 5;

    const u16* mats[3] = {A0, A1, A2};

    floatx16 acc[2][TJ];
#pragma unroll
    for (int ti = 0; ti < 2; ++ti)
#pragma unroll
        for (int tj = 0; tj < TJ; ++tj)
#pragma unroll
            for (int r = 0; r < 16; ++r) acc[ti][tj][r] = 0.f;

    for (int c = 0; c < 6; ++c) {
        const u16* M = mats[c >> 1];
        const int kloc = (c & 1) * 64;
#pragma unroll
        for (int it = 0; it < 4; ++it) {
            int rib  = wave * 32 + it * 8 + (lane >> 3);
            int grow = row0 + rib;
            if (grow >= n) grow = n - 1;
            uint4 v = *(const uint4*)(M + (size_t)grow * 128 + kloc + (lane & 7) * 8);
            int cc = (lane & 7) ^ (rib & 7);
            *(uint4*)&As[rib * 64 + cc * 8] = v;
        }
        {
            const int cbase = c * BELEMS;
#pragma unroll
            for (int j = 0; j < BELEMS / 2048; ++j) {
                int idx  = tid + j * 256;
                int nrow = idx >> 3, seg = idx & 7;
                int dcc  = seg ^ (nrow & 7);
                *(uint4*)&Bh[nrow * 64 + dcc * 8] =
                    *(const uint4*)(whi + cbase + idx * 8);
                *(uint4*)&Bl[nrow * 64 + dcc * 8] =
                    *(const uint4*)(wlo + cbase + idx * 8);
            }
        }
        __syncthreads();
#pragma unroll
        for (int s = 0; s < 4; ++s) {
            const int cc = s * 2 + half;
            short8 a[2], bhf[TJ], blf[TJ];
#pragma unroll
            for (int ti = 0; ti < 2; ++ti) {
                int r = wrow * 64 + ti * 32 + m;
                a[ti] = *(const short8*)&As[r * 64 + ((cc ^ (r & 7)) * 8)];
            }
#pragma unroll
            for (int tj = 0; tj < TJ; ++tj) {
                int rr = wcol * TJ * 32 + tj * 32 + m;
                int off = rr * 64 + ((cc ^ (rr & 7)) * 8);
                bhf[tj] = *(const short8*)&Bh[off];
                blf[tj] = *(const short8*)&Bl[off];
            }
#pragma unroll
            for (int ti = 0; ti < 2; ++ti)
#pragma unroll
                for (int tj = 0; tj < TJ; ++tj) {
                    acc[ti][tj] = __builtin_amdgcn_mfma_f32_32x32x16_bf16(
                        a[ti], bhf[tj], acc[ti][tj], 0, 0, 0);
                    acc[ti][tj] = __builtin_amdgcn_mfma_f32_32x32x16_bf16(
                        a[ti], blf[tj], acc[ti][tj], 0, 0, 0);
                }
        }
        __syncthreads();
    }

    // ---- epilogue: store C + fused BN stats ----
    if (tid < DOUT) { col_s[tid] = 0.f; col_q[tid] = 0.f; }
    __syncthreads();
#pragma unroll
    for (int tj = 0; tj < TJ; ++tj) {
        int gcol = (wcol * TJ + tj) * 32 + m;
        float s = 0.f, qq = 0.f;
#pragma unroll
        for (int ti = 0; ti < 2; ++ti)
#pragma unroll
            for (int r = 0; r < 16; ++r) {
                int grow = row0 + wrow * 64 + ti * 32 + (r & 3) + 8 * (r >> 2) + 4 * half;
                if (grow < n) {
                    float v = acc[ti][tj][r];
                    s += v; qq += v * v;
                    outp[(size_t)grow * DOUT + gcol] = (u16)f2bf(v);
                }
            }
        atomicAdd(&col_s[gcol], s);
        atomicAdd(&col_q[gcol], qq);
    }
    __syncthreads();
    if (tid < DOUT) {
        atomicAdd(&gstats[tid], col_s[tid]);
        atomicAdd(&gstats[DOUT + tid], col_q[tid]);
    }
}

// ---------------------------------------------------------------------------
// BN finalize / apply  (h stored bf16)
// stats layout: [sum(DOUT) | sumsq(DOUT) | scale(DOUT) | shift(DOUT)]
// ---------------------------------------------------------------------------
__global__ void bn_finalize(float* __restrict__ stats, const float* __restrict__ gamma,
                            const float* __restrict__ beta, int dout, float inv_n) {
    int c = threadIdx.x;
    if (c < dout) {
        float m = stats[c] * inv_n;
        float var = stats[dout + c] * inv_n - m * m;
        float sc = rsqrtf(var + BN_EPS) * gamma[c];
        stats[2 * dout + c] = sc;
        stats[3 * dout + c] = beta[c] - m * sc;
    }
}

template <int DOUT, bool SKIP>
__global__ __launch_bounds__(256)
void bn_apply(u16* __restrict__ h, const float* __restrict__ stats,
              const u16* __restrict__ skip, int total4) {
    constexpr int C4 = DOUT / 4;
    const float* scale = stats + 2 * DOUT;
    const float* shift = stats + 3 * DOUT;
    for (int idx = blockIdx.x * 256 + threadIdx.x; idx < total4; idx += gridDim.x * 256) {
        int c4 = (idx % C4) * 4;
        uint2 u = ((const uint2*)h)[idx];
        float v0 = bflo(u.x), v1 = bfhi(u.x), v2 = bflo(u.y), v3 = bfhi(u.y);
        v0 = fmaxf(fmaf(v0, scale[c4 + 0], shift[c4 + 0]), 0.f);
        v1 = fmaxf(fmaf(v1, scale[c4 + 1], shift[c4 + 1]), 0.f);
        v2 = fmaxf(fmaf(v2, scale[c4 + 2], shift[c4 + 2]), 0.f);
        v3 = fmaxf(fmaf(v3, scale[c4 + 3], shift[c4 + 3]), 0.f);
        if (SKIP) {
            uint2 sk = ((const uint2*)skip)[idx];
            v0 += bflo(sk.x); v1 += bfhi(sk.x); v2 += bflo(sk.y); v3 += bfhi(sk.y);
        }
        uint2 o; o.x = pack2(v0, v1); o.y = pack2(v2, v3);
        ((uint2*)h)[idx] = o;
    }
}

// ---------------------------------------------------------------------------
// graph boundaries from sorted segment_ids (parallel boundary detect)
// gstart[g] = min{i : seg[i] >= g}; gstart[G] = n
// ---------------------------------------------------------------------------
__global__ void gstart_kernel(const int* __restrict__ seg, int* __restrict__ gstart,
                              int n, int g_count) {
    int i = blockIdx.x * 256 + threadIdx.x;
    if (i >= n) return;
    int cur = seg[i];
    if (i == 0) {
        for (int g = 0; g <= cur; ++g) gstart[g] = 0;
    } else {
        int prev = seg[i - 1];
        for (int g = prev + 1; g <= cur; ++g) gstart[g] = i;
    }
    if (i == n - 1) {
        for (int g = cur + 1; g <= g_count; ++g) gstart[g] = n;
    }
}

// ---------------------------------------------------------------------------
// pooling: per-graph max/min/mean/std over h[N,64] (bf16); one wave per graph
// ---------------------------------------------------------------------------
__global__ __launch_bounds__(256)
void pool_kernel(const u16* __restrict__ h, const int* __restrict__ gstart,
                 float* __restrict__ pooled, int g_count) {
    int wave = threadIdx.x >> 6;
    int lane = threadIdx.x & 63;
    int g = blockIdx.x * 4 + wave;
    if (g >= g_count) return;
    int s = gstart[g], e = gstart[g + 1];
    float mx = -INFINITY, mn = INFINITY, sm = 0.f, sq = 0.f;
    for (int nidx = s; nidx < e; ++nidx) {
        float v = bf1(h[(size_t)nidx * 64 + lane]);
        mx = fmaxf(mx, v);
        mn = fminf(mn, v);
        sm += v;
        sq += v * v;
    }
    float cnt = (float)(e - s);
    float mean = sm / fmaxf(cnt, 1.f);
    float var = (sq - cnt * mean * mean) / fmaxf(cnt - 1.f, 1.f);
    float sd = sqrtf(fmaxf(var, 0.f));
    size_t base = (size_t)g * 256;
    pooled[base + 0 * 64 + lane] = mx;
    pooled[base + 1 * 64 + lane] = mn;
    pooled[base + 2 * 64 + lane] = mean;
    pooled[base + 3 * 64 + lane] = sd;
}

__global__ void agg_stats(const float* __restrict__ pooled, float* __restrict__ aggstat,
                          int g_count) {
    int ch = blockIdx.x;
    int total = g_count * 64;
    float s = 0.f, q = 0.f;
    for (int i = threadIdx.x; i < total; i += 256) {
        int g = i >> 6, f = i & 63;
        float v = pooled[(size_t)g * 256 + ch * 64 + f];
        s += v; q += v * v;
    }
    __shared__ float ls[256], lq[256];
    ls[threadIdx.x] = s; lq[threadIdx.x] = q;
    __syncthreads();
    for (int off = 128; off > 0; off >>= 1) {
        if (threadIdx.x < off) {
            ls[threadIdx.x] += ls[threadIdx.x + off];
            lq[threadIdx.x] += lq[threadIdx.x + off];
        }
        __syncthreads();
    }
    if (threadIdx.x == 0) {
        float inv = 1.f / (float)total;
        float m = ls[0] * inv;
        aggstat[ch * 2 + 0] = m;
        aggstat[ch * 2 + 1] = lq[0] * inv - m * m;
    }
}

__global__ __launch_bounds__(256)
void final_kernel(const float* __restrict__ pooled, const float* __restrict__ aggstat,
                  const float* __restrict__ agg_gamma, const float* __restrict__ agg_beta,
                  const float* __restrict__ aggW, const float* __restrict__ aggb,
                  const float* __restrict__ outW, const float* __restrict__ outb,
                  float* __restrict__ out, int g_count) {
    __shared__ float sflat[4][256];
    int wave = threadIdx.x >> 6;
    int lane = threadIdx.x & 63;
    int g = blockIdx.x * 4 + wave;
    if (g < g_count) {
#pragma unroll
        for (int c = 0; c < 4; ++c) {
            float v = pooled[(size_t)g * 256 + c * 64 + lane];
            float m = aggstat[c * 2], var = aggstat[c * 2 + 1];
            v = (v - m) * rsqrtf(var + BN_EPS) * agg_gamma[c] + agg_beta[c];
            sflat[wave][c * 64 + lane] = v;
        }
    }
    __syncthreads();
    if (g < g_count) {
        float acc = aggb[lane];
        const float* wrow = aggW + lane * 256;
#pragma unroll 8
        for (int i = 0; i < 256; ++i)
            acc = fmaf(sflat[wave][i], wrow[i], acc);
        float t = acc * outW[lane];
        for (int off = 32; off > 0; off >>= 1) t += __shfl_down(t, off, 64);
        if (lane == 0) out[g] = t + outb[0];
    }
}

// ---------------------------------------------------------------------------
// host launcher
// ---------------------------------------------------------------------------
extern "C" void kernel_launch(void* const* d_in, const int* in_sizes, int n_in,
                              void* d_out, int out_size, void* d_ws, size_t ws_size,
                              hipStream_t stream) {
    const int N = N_NODES, E = N_EDGES, G = N_GRAPHS;

    const float* x           = (const float*)d_in[0];
    const int*   ei          = (const int*)d_in[1];
    const int*   seg         = (const int*)d_in[2];
    const float* conv_W      = (const float*)d_in[3];
    const float* conv_W_last = (const float*)d_in[4];
    const float* bn_g        = (const float*)d_in[5];
    const float* bn_b        = (const float*)d_in[6];
    const float* bn_gl       = (const float*)d_in[7];
    const float* bn_bl       = (const float*)d_in[8];
    const float* agg_g       = (const float*)d_in[9];
    const float* agg_bt      = (const float*)d_in[10];
    const float* aggW        = (const float*)d_in[11];
    const float* aggb        = (const float*)d_in[12];
    const float* outW        = (const float*)d_in[13];
    const float* outb        = (const float*)d_in[14];
    float* out = (float*)d_out;

    const int* esrc = ei;
    const int* edst = ei + E;

    size_t off = 0;
    auto alloc = [&](size_t bytes) -> void* {
        void* p = (char*)d_ws + off;
        off += (bytes + 255) & ~(size_t)255;
        return p;
    };
    int*   deg_i  = (int*)alloc((size_t)N * 4);
    float* normv  = (float*)alloc((size_t)N * 4);
    int*   rowptr = (int*)alloc((size_t)(N + 1) * 4);
    int*   bsums  = (int*)alloc(128 * 4);
    int*   pos    = (int*)alloc((size_t)N * 4);
    int*   csr    = (int*)alloc((size_t)E * 4);
    int*   gstart = (int*)alloc((size_t)(G + 1) * 4);
    float* stats  = (float*)alloc(4 * 128 * 4);
    float* aggstat= (float*)alloc(8 * 4);
    float* pooled = (float*)alloc((size_t)G * 256 * 4);
    const size_t WPACK = 5 * 384 * 128 + 384 * 64;
    u16*   whip   = (u16*)alloc(WPACK * 2);
    u16*   wlop   = (u16*)alloc(WPACK * 2);
    u16*   ring0  = (u16*)alloc((size_t)N * 128 * 2);
    u16*   ring1  = (u16*)alloc((size_t)N * 128 * 2);
    u16*   ring2  = (u16*)alloc((size_t)N * 128 * 2);
    u16*   p1     = (u16*)alloc((size_t)N * 128 * 2);
    u16*   p2     = (u16*)alloc((size_t)N * 128 * 2);
    u16*   ring[3] = {ring0, ring1, ring2};

    // ---- degree + norm ----
    hipMemsetAsync(deg_i, 0, (size_t)N * 4, stream);
    deg_kernel<<<(E + 255) / 256, 256, 0, stream>>>(edst, deg_i, E);
    norm_kernel<<<(N + 255) / 256, 256, 0, stream>>>(deg_i, normv, N);

    // ---- x -> bf16 (into ring2; dead before layer 2 writes it) ----
    x2bf_kernel<<<2048, 256, 0, stream>>>(x, ring2, N * 128 / 4);

    // ---- W pack (hi/lo, transposed, chunked) ----
    for (int l = 0; l < 5; ++l)
        wpack_kernel<<<(384 * 128 + 255) / 256, 256, 0, stream>>>(
            conv_W + (size_t)l * 384 * 128, whip + (size_t)l * 384 * 128,
            wlop + (size_t)l * 384 * 128, 384, 128);
    wpack_kernel<<<(384 * 64 + 255) / 256, 256, 0, stream>>>(
        conv_W_last, whip + (size_t)5 * 384 * 128, wlop + (size_t)5 * 384 * 128, 384, 64);

    // ---- CSR build ----
    int nscan = (N + 2047) / 2048;
    scan_block_sums<<<nscan, 256, 0, stream>>>(deg_i, bsums, N);
    scan_exclusive_small<<<1, 128, 0, stream>>>(bsums, nscan);
    scan_final<<<nscan, 256, 0, stream>>>(deg_i, bsums, rowptr, N);
    copy_int_kernel<<<(N + 255) / 256, 256, 0, stream>>>(rowptr, pos, N);
    fill_csr<<<(E + 255) / 256, 256, 0, stream>>>(esrc, edst, pos, csr, E);

    // ---- graph boundaries ----
    gstart_kernel<<<(N + 255) / 256, 256, 0, stream>>>(seg, gstart, N, G);

    // ---- layers ----
    const u16* h_in = ring2;
    const int gemm_grid = (N + 127) / 128;
    for (int l = 0; l < 6; ++l) {
        const int dout = (l < 5) ? 128 : 64;
        const u16* whi = whip + (size_t)((l < 5) ? l * 384 * 128 : 5 * 384 * 128);
        const u16* wlo = wlop + (size_t)((l < 5) ? l * 384 * 128 : 5 * 384 * 128);
        const float* gamma = (l < 5) ? (bn_g + l * 128) : bn_gl;
        const float* beta  = (l < 5) ? (bn_b + l * 128) : bn_bl;
        u16* outbuf = ring[l % 3];

        prop_kernel<<<(N + 3) / 4, 256, 0, stream>>>(h_in, normv, rowptr, csr, p1, N);
        prop_kernel<<<(N + 3) / 4, 256, 0, stream>>>(p1, normv, rowptr, csr, p2, N);

        hipMemsetAsync(stats, 0, (size_t)2 * dout * 4, stream);
        if (dout == 128)
            gemm_mfma<128><<<gemm_grid, 256, 0, stream>>>(h_in, p1, p2, whi, wlo, outbuf,
                                                          stats, N);
        else
            gemm_mfma<64><<<gemm_grid, 256, 0, stream>>>(h_in, p1, p2, whi, wlo, outbuf,
                                                         stats, N);
        bn_finalize<<<1, 128, 0, stream>>>(stats, gamma, beta, dout, 1.f / (float)N);

        int total4 = N * dout / 4;
        bool has_skip = (l >= 2 && l < 5);
        const u16* skipb = has_skip ? ring[(l - 2) % 3] : nullptr;
        if (dout == 128) {
            if (has_skip)
                bn_apply<128, true><<<8192, 256, 0, stream>>>(outbuf, stats, skipb, total4);
            else
                bn_apply<128, false><<<8192, 256, 0, stream>>>(outbuf, stats, nullptr, total4);
        } else {
            bn_apply<64, false><<<8192, 256, 0, stream>>>(outbuf, stats, nullptr, total4);
        }
        h_in = outbuf;
    }

    // ---- pooling + head ----
    pool_kernel<<<(G + 3) / 4, 256, 0, stream>>>(ring[5 % 3], gstart, pooled, G);
    agg_stats<<<4, 256, 0, stream>>>(pooled, aggstat, G);
    final_kernel<<<(G + 3) / 4, 256, 0, stream>>>(pooled, aggstat, agg_g, agg_bt,
                                                  aggW, aggb, outW, outb, out, G);
}

// Round 5
// 2769.689 us; speedup vs baseline: 1.8974x; 1.0984x over previous
//
#include <hip/hip_runtime.h>
#include <cstddef>
#include <cstdint>

#define N_NODES  200000
#define N_EDGES  3200000
#define N_GRAPHS 2000
#define BN_EPS   1e-5f
#define NB       391          // ceil(N / 512) buckets
#define BSH      9            // bucket = dst >> 9 (512 nodes per bucket)
#define CHUNK    16384        // edges per block in hist/scatter

typedef unsigned int   u32;
typedef unsigned short u16;

using short8   = __attribute__((ext_vector_type(8))) short;
using floatx16 = __attribute__((ext_vector_type(16))) float;

// ---------------------------------------------------------------------------
// bf16 helpers (raw-bit, RNE pack)
// ---------------------------------------------------------------------------
__device__ __forceinline__ float bflo(u32 v) { union {u32 i; float f;} c; c.i = v << 16; return c.f; }
__device__ __forceinline__ float bfhi(u32 v) { union {u32 i; float f;} c; c.i = v & 0xffff0000u; return c.f; }
__device__ __forceinline__ float bf1(u16 v)  { union {u32 i; float f;} c; c.i = ((u32)v) << 16; return c.f; }
__device__ __forceinline__ u32 f2bf(float f) {
    union {float f; u32 i;} c; c.f = f;
    return (c.i + 0x7fffu + ((c.i >> 16) & 1u)) >> 16;
}
__device__ __forceinline__ u32 pack2(float a, float b) { return f2bf(a) | (f2bf(b) << 16); }

// ---------------------------------------------------------------------------
// x (fp32) -> bf16
// ---------------------------------------------------------------------------
__global__ void x2bf_kernel(const float* __restrict__ x, u16* __restrict__ xb, int total4) {
    for (int i = blockIdx.x * 256 + threadIdx.x; i < total4; i += gridDim.x * 256) {
        float4 v = ((const float4*)x)[i];
        uint2 o; o.x = pack2(v.x, v.y); o.y = pack2(v.z, v.w);
        ((uint2*)xb)[i] = o;
    }
}

// ---------------------------------------------------------------------------
// W pack: fp32 W[K,DOUT] -> transposed, K-chunked, hi/lo bf16
// ---------------------------------------------------------------------------
__global__ void wpack_kernel(const float* __restrict__ W, u16* __restrict__ whi,
                             u16* __restrict__ wlo, int K, int DOUT) {
    int tid = blockIdx.x * 256 + threadIdx.x;
    if (tid >= K * DOUT) return;
    int k = tid / DOUT, nn = tid % DOUT;
    float w = W[tid];
    u16 hi = (u16)f2bf(w);
    float rem = w - bf1(hi);
    u16 lo = (u16)f2bf(rem);
    int dst = (k >> 6) * DOUT * 64 + nn * 64 + (k & 63);
    whi[dst] = hi;
    wlo[dst] = lo;
}

// ---------------------------------------------------------------------------
// CSR build via 391-bucket multisplit (bucket = dst >> 9)
// ---------------------------------------------------------------------------
__global__ __launch_bounds__(256)
void bucket_hist(const int* __restrict__ edst, int* __restrict__ bcnt, int e) {
    __shared__ int h[NB];
    for (int t = threadIdx.x; t < NB; t += 256) h[t] = 0;
    __syncthreads();
    int base = blockIdx.x * CHUNK;
    int end  = min(base + CHUNK, e);
    for (int i = base + threadIdx.x; i < end; i += 256)
        atomicAdd(&h[edst[i] >> BSH], 1);
    __syncthreads();
    for (int t = threadIdx.x; t < NB; t += 256)
        if (h[t]) atomicAdd(&bcnt[t], h[t]);
}

__global__ void bucket_scan(const int* __restrict__ bcnt, int* __restrict__ bbase,
                            int* __restrict__ bcur) {
    __shared__ int ls[512];
    int t = threadIdx.x;
    int v = (t < NB) ? bcnt[t] : 0;
    ls[t] = v;
    __syncthreads();
    for (int off = 1; off < 512; off <<= 1) {
        int a = (t >= off) ? ls[t - off] : 0;
        __syncthreads();
        ls[t] += a;
        __syncthreads();
    }
    if (t <= NB) {
        int excl = ls[t] - v;
        bbase[t] = excl;
        if (t < NB) bcur[t] = excl;
    }
}

__global__ __launch_bounds__(256)
void bucket_scatter(const int* __restrict__ esrc, const int* __restrict__ edst,
                    int* __restrict__ bcur, uint2* __restrict__ esorted, int e) {
    __shared__ int h[NB], lbase[NB], lcur[NB];
    for (int t = threadIdx.x; t < NB; t += 256) { h[t] = 0; lcur[t] = 0; }
    __syncthreads();
    int base = blockIdx.x * CHUNK;
    int end  = min(base + CHUNK, e);
    for (int i = base + threadIdx.x; i < end; i += 256)
        atomicAdd(&h[edst[i] >> BSH], 1);
    __syncthreads();
    for (int t = threadIdx.x; t < NB; t += 256)
        lbase[t] = h[t] ? atomicAdd(&bcur[t], h[t]) : 0;
    __syncthreads();
    for (int i = base + threadIdx.x; i < end; i += 256) {
        int d = edst[i];
        int b = d >> BSH;
        int p = lbase[b] + atomicAdd(&lcur[b], 1);
        uint2 ed; ed.x = (u32)esrc[i]; ed.y = (u32)d;
        esorted[p] = ed;
    }
}

// One block per bucket: local count -> scan -> rowptr + norm -> CSR fill.
__global__ __launch_bounds__(256)
void bucket_fill(const uint2* __restrict__ esorted, const int* __restrict__ bbase,
                 int* __restrict__ rowptr, int* __restrict__ csr,
                 float* __restrict__ normv, int n, int e) {
    __shared__ int cnt[512], loc[512], tsum[256];
    const int b = blockIdx.x;
    const int ebeg = bbase[b], eend = bbase[b + 1];
    const int t = threadIdx.x;
    cnt[t] = 0; cnt[t + 256] = 0;
    __syncthreads();
    for (int i = ebeg + t; i < eend; i += 256)
        atomicAdd(&cnt[esorted[i].y & 511], 1);
    __syncthreads();
    int c0 = cnt[2 * t], c1 = cnt[2 * t + 1];
    tsum[t] = c0 + c1;
    __syncthreads();
    for (int off = 1; off < 256; off <<= 1) {
        int a = (t >= off) ? tsum[t - off] : 0;
        __syncthreads();
        tsum[t] += a;
        __syncthreads();
    }
    int excl = tsum[t] - (c0 + c1);
    loc[2 * t] = excl;
    loc[2 * t + 1] = excl + c0;
    __syncthreads();
    for (int j = t; j < 512; j += 256) {
        int node = (b << 9) + j;
        if (node < n) {
            rowptr[node] = ebeg + loc[j];
            int deg = cnt[j];
            normv[node] = (deg > 0) ? rsqrtf((float)deg) : 0.f;
        }
    }
    if (b == 0 && t == 0) rowptr[n] = e;
    __syncthreads();
    // reuse cnt as scatter cursor
    for (int j = t; j < 512; j += 256) cnt[j] = loc[j];
    __syncthreads();
    for (int i = ebeg + t; i < eend; i += 256) {
        uint2 ed = esorted[i];
        int slot = ebeg + atomicAdd(&cnt[ed.y & 511], 1);
        csr[slot] = (int)ed.x;
    }
}

// ---------------------------------------------------------------------------
// prop: p[dst] = norm[dst] * sum_{src in N(dst)} norm[src] * h[src]   (d = 128)
// Quarter-wave gather, unroll 4: wave = 1 node, lane = quarter*16 + fgroup.
// Each lane loads uint4 (8 bf16); 16 edges per wave-iteration.
// ---------------------------------------------------------------------------
__global__ __launch_bounds__(256)
void prop_kernel(const u16* __restrict__ hin, const float* __restrict__ norm,
                 const int* __restrict__ rowptr, const int* __restrict__ csr,
                 u16* __restrict__ pout, int n) {
    int wave = threadIdx.x >> 6;
    int lane = threadIdx.x & 63;
    int node = blockIdx.x * 4 + wave;
    if (node >= n) return;
    const int q = lane >> 4;
    const int f = (lane & 15) * 8;
    int s = rowptr[node], e = rowptr[node + 1];
    float a0 = 0, a1 = 0, a2 = 0, a3 = 0, a4 = 0, a5 = 0, a6 = 0, a7 = 0;
    int i = s + q;
    for (; i + 12 < e; i += 16) {
        int sn0 = csr[i], sn1 = csr[i + 4], sn2 = csr[i + 8], sn3 = csr[i + 12];
        float nw0 = norm[sn0], nw1 = norm[sn1], nw2 = norm[sn2], nw3 = norm[sn3];
        uint4 v0 = *(const uint4*)(hin + (size_t)sn0 * 128 + f);
        uint4 v1 = *(const uint4*)(hin + (size_t)sn1 * 128 + f);
        uint4 v2 = *(const uint4*)(hin + (size_t)sn2 * 128 + f);
        uint4 v3 = *(const uint4*)(hin + (size_t)sn3 * 128 + f);
        a0 += bflo(v0.x) * nw0 + bflo(v1.x) * nw1 + bflo(v2.x) * nw2 + bflo(v3.x) * nw3;
        a1 += bfhi(v0.x) * nw0 + bfhi(v1.x) * nw1 + bfhi(v2.x) * nw2 + bfhi(v3.x) * nw3;
        a2 += bflo(v0.y) * nw0 + bflo(v1.y) * nw1 + bflo(v2.y) * nw2 + bflo(v3.y) * nw3;
        a3 += bfhi(v0.y) * nw0 + bfhi(v1.y) * nw1 + bfhi(v2.y) * nw2 + bfhi(v3.y) * nw3;
        a4 += bflo(v0.z) * nw0 + bflo(v1.z) * nw1 + bflo(v2.z) * nw2 + bflo(v3.z) * nw3;
        a5 += bfhi(v0.z) * nw0 + bfhi(v1.z) * nw1 + bfhi(v2.z) * nw2 + bfhi(v3.z) * nw3;
        a6 += bflo(v0.w) * nw0 + bflo(v1.w) * nw1 + bflo(v2.w) * nw2 + bflo(v3.w) * nw3;
        a7 += bfhi(v0.w) * nw0 + bfhi(v1.w) * nw1 + bfhi(v2.w) * nw2 + bfhi(v3.w) * nw3;
    }
    for (; i < e; i += 4) {
        int sn0 = csr[i];
        float nw0 = norm[sn0];
        uint4 v0 = *(const uint4*)(hin + (size_t)sn0 * 128 + f);
        a0 += bflo(v0.x) * nw0; a1 += bfhi(v0.x) * nw0;
        a2 += bflo(v0.y) * nw0; a3 += bfhi(v0.y) * nw0;
        a4 += bflo(v0.z) * nw0; a5 += bfhi(v0.z) * nw0;
        a6 += bflo(v0.w) * nw0; a7 += bfhi(v0.w) * nw0;
    }
    a0 += __shfl_down(a0, 32, 64); a1 += __shfl_down(a1, 32, 64);
    a2 += __shfl_down(a2, 32, 64); a3 += __shfl_down(a3, 32, 64);
    a4 += __shfl_down(a4, 32, 64); a5 += __shfl_down(a5, 32, 64);
    a6 += __shfl_down(a6, 32, 64); a7 += __shfl_down(a7, 32, 64);
    a0 += __shfl_down(a0, 16, 64); a1 += __shfl_down(a1, 16, 64);
    a2 += __shfl_down(a2, 16, 64); a3 += __shfl_down(a3, 16, 64);
    a4 += __shfl_down(a4, 16, 64); a5 += __shfl_down(a5, 16, 64);
    a6 += __shfl_down(a6, 16, 64); a7 += __shfl_down(a7, 16, 64);
    if (q == 0) {
        float nd = norm[node];
        uint4 o;
        o.x = pack2(a0 * nd, a1 * nd);
        o.y = pack2(a2 * nd, a3 * nd);
        o.z = pack2(a4 * nd, a5 * nd);
        o.w = pack2(a6 * nd, a7 * nd);
        *(uint4*)(pout + (size_t)node * 128 + f) = o;
    }
}

// ---------------------------------------------------------------------------
// MFMA GEMM + fused BN stats
// ---------------------------------------------------------------------------
template <int DOUT>
__global__ __launch_bounds__(256)
void gemm_mfma(const u16* __restrict__ A0, const u16* __restrict__ A1,
               const u16* __restrict__ A2, const u16* __restrict__ whi,
               const u16* __restrict__ wlo, u16* __restrict__ outp,
               float* __restrict__ gstats, int n) {
    constexpr int TJ = DOUT / 64;
    constexpr int BELEMS = DOUT * 64;
    __shared__ u16 As[128 * 64];
    __shared__ u16 Bh[BELEMS];
    __shared__ u16 Bl[BELEMS];
    __shared__ float col_s[DOUT];
    __shared__ float col_q[DOUT];

    const int tid  = threadIdx.x;
    const int wave = tid >> 6;
    const int lane = tid & 63;
    const int wrow = wave >> 1;
    const int wcol = wave & 1;
    const int row0 = blockIdx.x * 128;
    const int m    = lane & 31;
    const int half = lane >> 5;

    const u16* mats[3] = {A0, A1, A2};

    floatx16 acc[2][TJ];
#pragma unroll
    for (int ti = 0; ti < 2; ++ti)
#pragma unroll
        for (int tj = 0; tj < TJ; ++tj)
#pragma unroll
            for (int r = 0; r < 16; ++r) acc[ti][tj][r] = 0.f;

    for (int c = 0; c < 6; ++c) {
        const u16* M = mats[c >> 1];
        const int kloc = (c & 1) * 64;
#pragma unroll
        for (int it = 0; it < 4; ++it) {
            int rib  = wave * 32 + it * 8 + (lane >> 3);
            int grow = row0 + rib;
            if (grow >= n) grow = n - 1;
            uint4 v = *(const uint4*)(M + (size_t)grow * 128 + kloc + (lane & 7) * 8);
            int cc = (lane & 7) ^ (rib & 7);
            *(uint4*)&As[rib * 64 + cc * 8] = v;
        }
        {
            const int cbase = c * BELEMS;
#pragma unroll
            for (int j = 0; j < BELEMS / 2048; ++j) {
                int idx  = tid + j * 256;
                int nrow = idx >> 3, seg = idx & 7;
                int dcc  = seg ^ (nrow & 7);
                *(uint4*)&Bh[nrow * 64 + dcc * 8] =
                    *(const uint4*)(whi + cbase + idx * 8);
                *(uint4*)&Bl[nrow * 64 + dcc * 8] =
                    *(const uint4*)(wlo + cbase + idx * 8);
            }
        }
        __syncthreads();
#pragma unroll
        for (int s = 0; s < 4; ++s) {
            const int cc = s * 2 + half;
            short8 a[2], bhf[TJ], blf[TJ];
#pragma unroll
            for (int ti = 0; ti < 2; ++ti) {
                int r = wrow * 64 + ti * 32 + m;
                a[ti] = *(const short8*)&As[r * 64 + ((cc ^ (r & 7)) * 8)];
            }
#pragma unroll
            for (int tj = 0; tj < TJ; ++tj) {
                int rr = wcol * TJ * 32 + tj * 32 + m;
                int off = rr * 64 + ((cc ^ (rr & 7)) * 8);
                bhf[tj] = *(const short8*)&Bh[off];
                blf[tj] = *(const short8*)&Bl[off];
            }
#pragma unroll
            for (int ti = 0; ti < 2; ++ti)
#pragma unroll
                for (int tj = 0; tj < TJ; ++tj) {
                    acc[ti][tj] = __builtin_amdgcn_mfma_f32_32x32x16_bf16(
                        a[ti], bhf[tj], acc[ti][tj], 0, 0, 0);
                    acc[ti][tj] = __builtin_amdgcn_mfma_f32_32x32x16_bf16(
                        a[ti], blf[tj], acc[ti][tj], 0, 0, 0);
                }
        }
        __syncthreads();
    }

    if (tid < DOUT) { col_s[tid] = 0.f; col_q[tid] = 0.f; }
    __syncthreads();
#pragma unroll
    for (int tj = 0; tj < TJ; ++tj) {
        int gcol = (wcol * TJ + tj) * 32 + m;
        float s = 0.f, qq = 0.f;
#pragma unroll
        for (int ti = 0; ti < 2; ++ti)
#pragma unroll
            for (int r = 0; r < 16; ++r) {
                int grow = row0 + wrow * 64 + ti * 32 + (r & 3) + 8 * (r >> 2) + 4 * half;
                if (grow < n) {
                    float v = acc[ti][tj][r];
                    s += v; qq += v * v;
                    outp[(size_t)grow * DOUT + gcol] = (u16)f2bf(v);
                }
            }
        atomicAdd(&col_s[gcol], s);
        atomicAdd(&col_q[gcol], qq);
    }
    __syncthreads();
    if (tid < DOUT) {
        atomicAdd(&gstats[tid], col_s[tid]);
        atomicAdd(&gstats[DOUT + tid], col_q[tid]);
    }
}

// ---------------------------------------------------------------------------
// BN finalize / apply
// ---------------------------------------------------------------------------
__global__ void bn_finalize(float* __restrict__ stats, const float* __restrict__ gamma,
                            const float* __restrict__ beta, int dout, float inv_n) {
    int c = threadIdx.x;
    if (c < dout) {
        float m = stats[c] * inv_n;
        float var = stats[dout + c] * inv_n - m * m;
        float sc = rsqrtf(var + BN_EPS) * gamma[c];
        stats[2 * dout + c] = sc;
        stats[3 * dout + c] = beta[c] - m * sc;
    }
}

template <int DOUT, bool SKIP>
__global__ __launch_bounds__(256)
void bn_apply(u16* __restrict__ h, const float* __restrict__ stats,
              const u16* __restrict__ skip, int total4) {
    constexpr int C4 = DOUT / 4;
    const float* scale = stats + 2 * DOUT;
    const float* shift = stats + 3 * DOUT;
    for (int idx = blockIdx.x * 256 + threadIdx.x; idx < total4; idx += gridDim.x * 256) {
        int c4 = (idx % C4) * 4;
        uint2 u = ((const uint2*)h)[idx];
        float v0 = bflo(u.x), v1 = bfhi(u.x), v2 = bflo(u.y), v3 = bfhi(u.y);
        v0 = fmaxf(fmaf(v0, scale[c4 + 0], shift[c4 + 0]), 0.f);
        v1 = fmaxf(fmaf(v1, scale[c4 + 1], shift[c4 + 1]), 0.f);
        v2 = fmaxf(fmaf(v2, scale[c4 + 2], shift[c4 + 2]), 0.f);
        v3 = fmaxf(fmaf(v3, scale[c4 + 3], shift[c4 + 3]), 0.f);
        if (SKIP) {
            uint2 sk = ((const uint2*)skip)[idx];
            v0 += bflo(sk.x); v1 += bfhi(sk.x); v2 += bflo(sk.y); v3 += bfhi(sk.y);
        }
        uint2 o; o.x = pack2(v0, v1); o.y = pack2(v2, v3);
        ((uint2*)h)[idx] = o;
    }
}

// ---------------------------------------------------------------------------
// graph boundaries from sorted segment_ids
// ---------------------------------------------------------------------------
__global__ void gstart_kernel(const int* __restrict__ seg, int* __restrict__ gstart,
                              int n, int g_count) {
    int i = blockIdx.x * 256 + threadIdx.x;
    if (i >= n) return;
    int cur = seg[i];
    if (i == 0) {
        for (int g = 0; g <= cur; ++g) gstart[g] = 0;
    } else {
        int prev = seg[i - 1];
        for (int g = prev + 1; g <= cur; ++g) gstart[g] = i;
    }
    if (i == n - 1) {
        for (int g = cur + 1; g <= g_count; ++g) gstart[g] = n;
    }
}

// ---------------------------------------------------------------------------
// pooling + head
// ---------------------------------------------------------------------------
__global__ __launch_bounds__(256)
void pool_kernel(const u16* __restrict__ h, const int* __restrict__ gstart,
                 float* __restrict__ pooled, int g_count) {
    int wave = threadIdx.x >> 6;
    int lane = threadIdx.x & 63;
    int g = blockIdx.x * 4 + wave;
    if (g >= g_count) return;
    int s = gstart[g], e = gstart[g + 1];
    float mx = -INFINITY, mn = INFINITY, sm = 0.f, sq = 0.f;
    for (int nidx = s; nidx < e; ++nidx) {
        float v = bf1(h[(size_t)nidx * 64 + lane]);
        mx = fmaxf(mx, v);
        mn = fminf(mn, v);
        sm += v;
        sq += v * v;
    }
    float cnt = (float)(e - s);
    float mean = sm / fmaxf(cnt, 1.f);
    float var = (sq - cnt * mean * mean) / fmaxf(cnt - 1.f, 1.f);
    float sd = sqrtf(fmaxf(var, 0.f));
    size_t base = (size_t)g * 256;
    pooled[base + 0 * 64 + lane] = mx;
    pooled[base + 1 * 64 + lane] = mn;
    pooled[base + 2 * 64 + lane] = mean;
    pooled[base + 3 * 64 + lane] = sd;
}

__global__ void agg_stats(const float* __restrict__ pooled, float* __restrict__ aggstat,
                          int g_count) {
    int ch = blockIdx.x;
    int total = g_count * 64;
    float s = 0.f, q = 0.f;
    for (int i = threadIdx.x; i < total; i += 256) {
        int g = i >> 6, f = i & 63;
        float v = pooled[(size_t)g * 256 + ch * 64 + f];
        s += v; q += v * v;
    }
    __shared__ float ls[256], lq[256];
    ls[threadIdx.x] = s; lq[threadIdx.x] = q;
    __syncthreads();
    for (int off = 128; off > 0; off >>= 1) {
        if (threadIdx.x < off) {
            ls[threadIdx.x] += ls[threadIdx.x + off];
            lq[threadIdx.x] += lq[threadIdx.x + off];
        }
        __syncthreads();
    }
    if (threadIdx.x == 0) {
        float inv = 1.f / (float)total;
        float m = ls[0] * inv;
        aggstat[ch * 2 + 0] = m;
        aggstat[ch * 2 + 1] = lq[0] * inv - m * m;
    }
}

__global__ __launch_bounds__(256)
void final_kernel(const float* __restrict__ pooled, const float* __restrict__ aggstat,
                  const float* __restrict__ agg_gamma, const float* __restrict__ agg_beta,
                  const float* __restrict__ aggW, const float* __restrict__ aggb,
                  const float* __restrict__ outW, const float* __restrict__ outb,
                  float* __restrict__ out, int g_count) {
    __shared__ float sflat[4][256];
    int wave = threadIdx.x >> 6;
    int lane = threadIdx.x & 63;
    int g = blockIdx.x * 4 + wave;
    if (g < g_count) {
#pragma unroll
        for (int c = 0; c < 4; ++c) {
            float v = pooled[(size_t)g * 256 + c * 64 + lane];
            float m = aggstat[c * 2], var = aggstat[c * 2 + 1];
            v = (v - m) * rsqrtf(var + BN_EPS) * agg_gamma[c] + agg_beta[c];
            sflat[wave][c * 64 + lane] = v;
        }
    }
    __syncthreads();
    if (g < g_count) {
        float acc = aggb[lane];
        const float* wrow = aggW + lane * 256;
#pragma unroll 8
        for (int i = 0; i < 256; ++i)
            acc = fmaf(sflat[wave][i], wrow[i], acc);
        float t = acc * outW[lane];
        for (int off = 32; off > 0; off >>= 1) t += __shfl_down(t, off, 64);
        if (lane == 0) out[g] = t + outb[0];
    }
}

// ---------------------------------------------------------------------------
// host launcher
// ---------------------------------------------------------------------------
extern "C" void kernel_launch(void* const* d_in, const int* in_sizes, int n_in,
                              void* d_out, int out_size, void* d_ws, size_t ws_size,
                              hipStream_t stream) {
    const int N = N_NODES, E = N_EDGES, G = N_GRAPHS;

    const float* x           = (const float*)d_in[0];
    const int*   ei          = (const int*)d_in[1];
    const int*   seg         = (const int*)d_in[2];
    const float* conv_W      = (const float*)d_in[3];
    const float* conv_W_last = (const float*)d_in[4];
    const float* bn_g        = (const float*)d_in[5];
    const float* bn_b        = (const float*)d_in[6];
    const float* bn_gl       = (const float*)d_in[7];
    const float* bn_bl       = (const float*)d_in[8];
    const float* agg_g       = (const float*)d_in[9];
    const float* agg_bt      = (const float*)d_in[10];
    const float* aggW        = (const float*)d_in[11];
    const float* aggb        = (const float*)d_in[12];
    const float* outW        = (const float*)d_in[13];
    const float* outb        = (const float*)d_in[14];
    float* out = (float*)d_out;

    const int* esrc = ei;
    const int* edst = ei + E;

    size_t off = 0;
    auto alloc = [&](size_t bytes) -> void* {
        void* p = (char*)d_ws + off;
        off += (bytes + 255) & ~(size_t)255;
        return p;
    };
    float* normv  = (float*)alloc((size_t)N * 4);
    int*   rowptr = (int*)alloc((size_t)(N + 1) * 4);
    int*   csr    = (int*)alloc((size_t)E * 4);
    int*   bcnt   = (int*)alloc((NB + 1) * 4);
    int*   bbase  = (int*)alloc((NB + 1) * 4);
    int*   bcur   = (int*)alloc((NB + 1) * 4);
    int*   gstart = (int*)alloc((size_t)(G + 1) * 4);
    float* stats  = (float*)alloc(4 * 128 * 4);
    float* aggstat= (float*)alloc(8 * 4);
    float* pooled = (float*)alloc((size_t)G * 256 * 4);
    const size_t WPACK = 5 * 384 * 128 + 384 * 64;
    u16*   whip   = (u16*)alloc(WPACK * 2);
    u16*   wlop   = (u16*)alloc(WPACK * 2);
    u16*   ring0  = (u16*)alloc((size_t)N * 128 * 2);
    u16*   ring1  = (u16*)alloc((size_t)N * 128 * 2);
    u16*   ring2  = (u16*)alloc((size_t)N * 128 * 2);
    u16*   p1     = (u16*)alloc((size_t)N * 128 * 2);
    u16*   p2     = (u16*)alloc((size_t)N * 128 * 2);
    u16*   ring[3] = {ring0, ring1, ring2};
    uint2* esorted = (uint2*)p2;   // alias: dead before first prop2 writes p2

    // ---- CSR build (multisplit) + norm ----
    hipMemsetAsync(bcnt, 0, (NB + 1) * 4, stream);
    const int nchunk = (E + CHUNK - 1) / CHUNK;
    bucket_hist<<<nchunk, 256, 0, stream>>>(edst, bcnt, E);
    bucket_scan<<<1, 512, 0, stream>>>(bcnt, bbase, bcur);
    bucket_scatter<<<nchunk, 256, 0, stream>>>(esrc, edst, bcur, esorted, E);
    bucket_fill<<<NB, 256, 0, stream>>>(esorted, bbase, rowptr, csr, normv, N, E);

    // ---- x -> bf16 (into ring2; dead before layer 2 writes it) ----
    x2bf_kernel<<<2048, 256, 0, stream>>>(x, ring2, N * 128 / 4);

    // ---- W pack ----
    for (int l = 0; l < 5; ++l)
        wpack_kernel<<<(384 * 128 + 255) / 256, 256, 0, stream>>>(
            conv_W + (size_t)l * 384 * 128, whip + (size_t)l * 384 * 128,
            wlop + (size_t)l * 384 * 128, 384, 128);
    wpack_kernel<<<(384 * 64 + 255) / 256, 256, 0, stream>>>(
        conv_W_last, whip + (size_t)5 * 384 * 128, wlop + (size_t)5 * 384 * 128, 384, 64);

    // ---- graph boundaries ----
    gstart_kernel<<<(N + 255) / 256, 256, 0, stream>>>(seg, gstart, N, G);

    // ---- layers ----
    const u16* h_in = ring2;
    const int gemm_grid = (N + 127) / 128;
    for (int l = 0; l < 6; ++l) {
        const int dout = (l < 5) ? 128 : 64;
        const u16* whi = whip + (size_t)((l < 5) ? l * 384 * 128 : 5 * 384 * 128);
        const u16* wlo = wlop + (size_t)((l < 5) ? l * 384 * 128 : 5 * 384 * 128);
        const float* gamma = (l < 5) ? (bn_g + l * 128) : bn_gl;
        const float* beta  = (l < 5) ? (bn_b + l * 128) : bn_bl;
        u16* outbuf = ring[l % 3];

        prop_kernel<<<(N + 3) / 4, 256, 0, stream>>>(h_in, normv, rowptr, csr, p1, N);
        prop_kernel<<<(N + 3) / 4, 256, 0, stream>>>(p1, normv, rowptr, csr, p2, N);

        hipMemsetAsync(stats, 0, (size_t)2 * dout * 4, stream);
        if (dout == 128)
            gemm_mfma<128><<<gemm_grid, 256, 0, stream>>>(h_in, p1, p2, whi, wlo, outbuf,
                                                          stats, N);
        else
            gemm_mfma<64><<<gemm_grid, 256, 0, stream>>>(h_in, p1, p2, whi, wlo, outbuf,
                                                         stats, N);
        bn_finalize<<<1, 128, 0, stream>>>(stats, gamma, beta, dout, 1.f / (float)N);

        int total4 = N * dout / 4;
        bool has_skip = (l >= 2 && l < 5);
        const u16* skipb = has_skip ? ring[(l - 2) % 3] : nullptr;
        if (dout == 128) {
            if (has_skip)
                bn_apply<128, true><<<8192, 256, 0, stream>>>(outbuf, stats, skipb, total4);
            else
                bn_apply<128, false><<<8192, 256, 0, stream>>>(outbuf, stats, nullptr, total4);
        } else {
            bn_apply<64, false><<<8192, 256, 0, stream>>>(outbuf, stats, nullptr, total4);
        }
        h_in = outbuf;
    }

    // ---- pooling + head ----
    pool_kernel<<<(G + 3) / 4, 256, 0, stream>>>(ring[5 % 3], gstart, pooled, G);
    agg_stats<<<4, 256, 0, stream>>>(pooled, aggstat, G);
    final_kernel<<<(G + 3) / 4, 256, 0, stream>>>(pooled, aggstat, agg_g, agg_bt,
                                                  aggW, aggb, outW, outb, out, G);
}